// Round 2
// baseline (283.810 us; speedup 1.0000x reference)
//
#include <hip/hip_runtime.h>

#define N_NODES 50000
#define NEG_SLOPE 0.2f

typedef short s8v __attribute__((ext_vector_type(8)));
typedef float f4v __attribute__((ext_vector_type(4)));

// ---- bf16 helpers (RNE) ---------------------------------------------------
__device__ __forceinline__ ushort f2bf(float f) {
  union { float f; unsigned u; } v; v.f = f;
  return (ushort)((v.u + 0x7FFFu + ((v.u >> 16) & 1u)) >> 16);
}
__device__ __forceinline__ float bf2f(ushort h) {
  union { unsigned u; float f; } v; v.u = ((unsigned)h) << 16;
  return v.f;
}

// ---- both weight transposes in one kernel ---------------------------------
__global__ void convT2_kernel(const float* __restrict__ W0, ushort* __restrict__ W0T,
                              const float* __restrict__ W1, ushort* __restrict__ W1T) {
  int i = blockIdx.x * blockDim.x + threadIdx.x;
  if (i < 32768) {
    int r = i >> 8, c = i & 255;           // W0: R=128, C=256
    W0T[c * 128 + r] = f2bf(W0[i]);
  } else {
    int j = i - 32768;
    int r = j >> 7, c = j & 127;           // W1: R=256, C=128
    W1T[c * 256 + r] = f2bf(W1[j]);
  }
}

// ---- MFMA GEMM, 64M x 128N tile + direct-store attention scores -----------
// R8/R10-proven structure — DO NOT restructure (R9's rewrite was flaky).
template <int HEADS, bool AF32>
__global__ __launch_bounds__(256) void gemm_mfma(
    const void* __restrict__ Av, const ushort* __restrict__ BT,
    ushort* __restrict__ C, int M, int N, int K,
    const float* __restrict__ a_src, const float* __restrict__ a_dst,
    float* __restrict__ ss, float* __restrict__ sd) {
  __shared__ ushort As[64][136];   // +8 pad: 16B-aligned, 2-way banks (free)
  __shared__ ushort Bs[128][136];
  const int tid = threadIdx.x;
  const int w = tid >> 6, lane = tid & 63;
  const int q = lane >> 4, r16 = lane & 15;
  const int n0 = blockIdx.x * 128, m0 = blockIdx.y * 64;
  f4v acc[8] = {};
  for (int kc = 0; kc < K; kc += 128) {
#pragma unroll
    for (int i = 0; i < 4; ++i) {
      int c = tid + 256 * i;
      int row = c >> 4, ko = (c & 15) * 8;
      int gm = m0 + row;
      s8v va = {};
      if (gm < M) {
        if (AF32) {
          const float* A = (const float*)Av;
          float4 f0 = *reinterpret_cast<const float4*>(&A[(size_t)gm * K + kc + ko]);
          float4 f1 = *reinterpret_cast<const float4*>(&A[(size_t)gm * K + kc + ko + 4]);
          va[0] = (short)f2bf(f0.x); va[1] = (short)f2bf(f0.y);
          va[2] = (short)f2bf(f0.z); va[3] = (short)f2bf(f0.w);
          va[4] = (short)f2bf(f1.x); va[5] = (short)f2bf(f1.y);
          va[6] = (short)f2bf(f1.z); va[7] = (short)f2bf(f1.w);
        } else {
          const ushort* A = (const ushort*)Av;
          va = *reinterpret_cast<const s8v*>(&A[(size_t)gm * K + kc + ko]);
        }
      }
      *reinterpret_cast<s8v*>(&As[row][ko]) = va;
    }
#pragma unroll
    for (int i = 0; i < 8; ++i) {
      int c = tid + 256 * i;
      int row = c >> 4, ko = (c & 15) * 8;
      s8v vb = *reinterpret_cast<const s8v*>(&BT[(size_t)(n0 + row) * K + kc + ko]);
      *reinterpret_cast<s8v*>(&Bs[row][ko]) = vb;
    }
    __syncthreads();
#pragma unroll
    for (int ks = 0; ks < 4; ++ks) {
      s8v af = *reinterpret_cast<const s8v*>(&As[w * 16 + r16][ks * 32 + q * 8]);
#pragma unroll
      for (int nt = 0; nt < 8; ++nt) {
        s8v bf = *reinterpret_cast<const s8v*>(&Bs[nt * 16 + r16][ks * 32 + q * 8]);
        acc[nt] = __builtin_amdgcn_mfma_f32_16x16x32_bf16(af, bf, acc[nt], 0, 0, 0);
      }
    }
    __syncthreads();
  }
#pragma unroll
  for (int nt = 0; nt < 8; ++nt)
#pragma unroll
    for (int r = 0; r < 4; ++r) {
      int gm = m0 + w * 16 + q * 4 + r;
      if (gm < M) C[(size_t)gm * N + n0 + nt * 16 + r16] = f2bf(acc[nt][r]);
    }
  const int head = n0 >> 7;
  float ps[4] = {0.f, 0.f, 0.f, 0.f}, pd[4] = {0.f, 0.f, 0.f, 0.f};
#pragma unroll
  for (int nt = 0; nt < 8; ++nt) {
    int n = n0 + nt * 16 + r16;
    float as = a_src[n], ad = a_dst[n];
#pragma unroll
    for (int r = 0; r < 4; ++r) {
      ps[r] = fmaf(acc[nt][r], as, ps[r]);
      pd[r] = fmaf(acc[nt][r], ad, pd[r]);
    }
  }
#pragma unroll
  for (int off = 1; off < 16; off <<= 1) {
#pragma unroll
    for (int r = 0; r < 4; ++r) {
      ps[r] += __shfl_xor(ps[r], off);
      pd[r] += __shfl_xor(pd[r], off);
    }
  }
  if (r16 == 0) {
#pragma unroll
    for (int r = 0; r < 4; ++r) {
      int gm = m0 + w * 16 + q * 4 + r;
      if (gm < M) {
        ss[gm * HEADS + head] = ps[r];
        sd[gm * HEADS + head] = pd[r];
      }
    }
  }
}

// ---- FUSED: layer-0 GEMM + CSR scatter in one dispatch --------------------
// gemm blocks (1564) and scatter blocks (nS) are INDEPENDENT (scatter's
// inputs rowptr/rank are complete before launch; gemm writes h0b/ss0/sd0).
// Interleave 1 gemm : 2 scatter in dispatch order for per-CU co-residency
// (MFMA pipe + memory pipe overlap; m114). gemm body verbatim from template.
#define NG0 1564  // 2 * ceil(N_NODES/64)
__global__ __launch_bounds__(256) void gemm0_scatter_kernel(
    const float* __restrict__ A, const ushort* __restrict__ BT,
    ushort* __restrict__ C, int M,
    const float* __restrict__ a_src, const float* __restrict__ a_dst,
    float* __restrict__ ss, float* __restrict__ sd,
    const int* __restrict__ ei, int E, int Etot, int nS,
    const int* __restrict__ rowptr, const ushort* __restrict__ rank,
    unsigned* __restrict__ csrSD) {
  __shared__ ushort As[64][136];
  __shared__ ushort Bs[128][136];
  const int id = blockIdx.x;
  int gemmIdx = -1, sIdx = -1;
  if (id < 3 * NG0) {
    const int g = id / 3, r = id % 3;
    if (r == 0) gemmIdx = g;
    else        sIdx = 2 * g + (r - 1);
  } else {
    sIdx = 2 * NG0 + (id - 3 * NG0);
  }

  if (gemmIdx >= 0) {
    // ---- gemm body (HEADS=2, AF32, N=256, K=128), x-major block order ----
    const int nb = gemmIdx & 1, mb = gemmIdx >> 1;
    const int tid = threadIdx.x;
    const int w = tid >> 6, lane = tid & 63;
    const int q = lane >> 4, r16 = lane & 15;
    const int n0 = nb * 128, m0 = mb * 64;
    const int N = 256, K = 128;
    f4v acc[8] = {};
    for (int kc = 0; kc < K; kc += 128) {
#pragma unroll
      for (int i = 0; i < 4; ++i) {
        int c = tid + 256 * i;
        int row = c >> 4, ko = (c & 15) * 8;
        int gm = m0 + row;
        s8v va = {};
        if (gm < M) {
          float4 f0 = *reinterpret_cast<const float4*>(&A[(size_t)gm * K + kc + ko]);
          float4 f1 = *reinterpret_cast<const float4*>(&A[(size_t)gm * K + kc + ko + 4]);
          va[0] = (short)f2bf(f0.x); va[1] = (short)f2bf(f0.y);
          va[2] = (short)f2bf(f0.z); va[3] = (short)f2bf(f0.w);
          va[4] = (short)f2bf(f1.x); va[5] = (short)f2bf(f1.y);
          va[6] = (short)f2bf(f1.z); va[7] = (short)f2bf(f1.w);
        }
        *reinterpret_cast<s8v*>(&As[row][ko]) = va;
      }
#pragma unroll
      for (int i = 0; i < 8; ++i) {
        int c = tid + 256 * i;
        int row = c >> 4, ko = (c & 15) * 8;
        s8v vb = *reinterpret_cast<const s8v*>(&BT[(size_t)(n0 + row) * K + kc + ko]);
        *reinterpret_cast<s8v*>(&Bs[row][ko]) = vb;
      }
      __syncthreads();
#pragma unroll
      for (int ks = 0; ks < 4; ++ks) {
        s8v af = *reinterpret_cast<const s8v*>(&As[w * 16 + r16][ks * 32 + q * 8]);
#pragma unroll
        for (int nt = 0; nt < 8; ++nt) {
          s8v bf = *reinterpret_cast<const s8v*>(&Bs[nt * 16 + r16][ks * 32 + q * 8]);
          acc[nt] = __builtin_amdgcn_mfma_f32_16x16x32_bf16(af, bf, acc[nt], 0, 0, 0);
        }
      }
      __syncthreads();
    }
#pragma unroll
    for (int nt = 0; nt < 8; ++nt)
#pragma unroll
      for (int r = 0; r < 4; ++r) {
        int gm = m0 + w * 16 + q * 4 + r;
        if (gm < M) C[(size_t)gm * N + n0 + nt * 16 + r16] = f2bf(acc[nt][r]);
      }
    const int head = n0 >> 7;
    float ps[4] = {0.f, 0.f, 0.f, 0.f}, pd[4] = {0.f, 0.f, 0.f, 0.f};
#pragma unroll
    for (int nt = 0; nt < 8; ++nt) {
      int n = n0 + nt * 16 + r16;
      float as = a_src[n], ad = a_dst[n];
#pragma unroll
      for (int r = 0; r < 4; ++r) {
        ps[r] = fmaf(acc[nt][r], as, ps[r]);
        pd[r] = fmaf(acc[nt][r], ad, pd[r]);
      }
    }
#pragma unroll
    for (int off = 1; off < 16; off <<= 1) {
#pragma unroll
      for (int r = 0; r < 4; ++r) {
        ps[r] += __shfl_xor(ps[r], off);
        pd[r] += __shfl_xor(pd[r], off);
      }
    }
    if (r16 == 0) {
#pragma unroll
      for (int r = 0; r < 4; ++r) {
        int gm = m0 + w * 16 + q * 4 + r;
        if (gm < M) {
          ss[gm * 2 + head] = ps[r];
          sd[gm * 2 + head] = pd[r];
        }
      }
    }
  } else {
    // ---- scatter body (verbatim from R12's scatter_kernel) ----
    if (sIdx >= nS) return;
    int e = sIdx * 256 + threadIdx.x;
    if (e >= Etot) return;
    int s, d;
    if (e < E) { s = ei[e]; d = ei[E + e]; } else { s = d = e - E; }
    csrSD[rowptr[d] + (int)rank[e]] = (unsigned)s | ((unsigned)d << 16);
  }
}

// ------------- CSR build: hist(+u16 rank) -> scan1 -> scan23 ---------------
__global__ void hist_kernel(const int* __restrict__ ei, int E, int Etot,
                            int* __restrict__ counts, ushort* __restrict__ rank) {
  int e = blockIdx.x * blockDim.x + threadIdx.x;
  if (e >= Etot) return;
  int d = (e < E) ? ei[E + e] : (e - E);
  rank[e] = (ushort)atomicAdd(&counts[d], 1);  // degree << 65536
}

__global__ __launch_bounds__(1024) void scan1_kernel(const int* __restrict__ counts,
                                                     int* __restrict__ partial,
                                                     int* __restrict__ blocksums, int n) {
  __shared__ int tmp[1024];
  int i = blockIdx.x * 1024 + threadIdx.x;
  int v = (i < n) ? counts[i] : 0;
  tmp[threadIdx.x] = v;
  __syncthreads();
  for (int off = 1; off < 1024; off <<= 1) {
    int t = (threadIdx.x >= off) ? tmp[threadIdx.x - off] : 0;
    __syncthreads();
    tmp[threadIdx.x] += t;
    __syncthreads();
  }
  if (i < n) partial[i] = tmp[threadIdx.x];
  if (threadIdx.x == 1023) blocksums[blockIdx.x] = tmp[1023];
}

__global__ void scan23_kernel(const int* __restrict__ partial,
                              const int* __restrict__ blocksums,
                              int* __restrict__ rowptr, int n, int nb) {
  __shared__ int sb[64];
  int t = threadIdx.x;
  if (t < 64) {
    int v = (t < nb) ? blocksums[t] : 0;
#pragma unroll
    for (int off = 1; off < 64; off <<= 1) {
      int u = __shfl_up(v, off);
      if ((t & 63) >= off) v += u;
    }
    sb[t] = v;
  }
  __syncthreads();
  int i = blockIdx.x * blockDim.x + t;
  if (i == 0) rowptr[0] = 0;
  if (i < n) {
    int b = i >> 10;
    int add = (b > 0) ? sb[b - 1] : 0;
    rowptr[i + 1] = partial[i] + add;
  }
}

// ---- layer-0 aggregation: whole-row wave, inline weights (R12-proven) -----
__global__ __launch_bounds__(256) void agg0_kernel(
    const ushort* __restrict__ h0,   // [N,256] bf16
    const float* __restrict__ ss, const float* __restrict__ sd,  // [N,2]
    const int* __restrict__ rowptr, const unsigned* __restrict__ csrSD,
    const float* __restrict__ b0, ushort* __restrict__ hE) {
  const int n = blockIdx.x * 4 + (threadIdx.x >> 6);
  const int t = threadIdx.x & 63;
  const int hd = t >> 5;
  const float sdn = sd[n * 2 + hd];
  float a0 = 0.f, a1 = 0.f, a2 = 0.f, a3 = 0.f, den = 0.f;
  int p = rowptr[n];
  const int p1 = rowptr[n + 1];
  for (; p + 4 <= p1; p += 4) {  // 4 rows in flight per wave
    int s[4];
#pragma unroll
    for (int j = 0; j < 4; ++j) s[j] = (int)(csrSD[p + j] & 0xFFFFu);
    ushort4 v[4];
#pragma unroll
    for (int j = 0; j < 4; ++j)
      v[j] = *reinterpret_cast<const ushort4*>(&h0[(size_t)s[j] * 256 + t * 4]);
    float w[4];
#pragma unroll
    for (int j = 0; j < 4; ++j) {
      float e = ss[s[j] * 2 + hd] + sdn;
      e = (e > 0.f) ? e : NEG_SLOPE * e;
      w[j] = __expf(e);
    }
#pragma unroll
    for (int j = 0; j < 4; ++j) {
      den += w[j];
      a0 = fmaf(w[j], bf2f(v[j].x), a0);
      a1 = fmaf(w[j], bf2f(v[j].y), a1);
      a2 = fmaf(w[j], bf2f(v[j].z), a2);
      a3 = fmaf(w[j], bf2f(v[j].w), a3);
    }
  }
  for (; p < p1; ++p) {
    const int sj = (int)(csrSD[p] & 0xFFFFu);
    float e = ss[sj * 2 + hd] + sdn;
    e = (e > 0.f) ? e : NEG_SLOPE * e;
    const float wj = __expf(e);
    const ushort4 vj = *reinterpret_cast<const ushort4*>(&h0[(size_t)sj * 256 + t * 4]);
    den += wj;
    a0 = fmaf(wj, bf2f(vj.x), a0); a1 = fmaf(wj, bf2f(vj.y), a1);
    a2 = fmaf(wj, bf2f(vj.z), a2); a3 = fmaf(wj, bf2f(vj.w), a3);
  }
  const float inv = 1.f / den;
  const float4 bv = reinterpret_cast<const float4*>(b0)[t];
  float o[4] = {fmaf(a0, inv, bv.x), fmaf(a1, inv, bv.y),
                fmaf(a2, inv, bv.z), fmaf(a3, inv, bv.w)};
#pragma unroll
  for (int i = 0; i < 4; ++i) o[i] = (o[i] > 0.f) ? o[i] : (__expf(o[i]) - 1.f);
  ushort4 ov; ov.x = f2bf(o[0]); ov.y = f2bf(o[1]); ov.z = f2bf(o[2]); ov.w = f2bf(o[3]);
  *reinterpret_cast<ushort4*>(&hE[(size_t)n * 256 + t * 4]) = ov;
}

// ---- layer-1 aggregation: inline edge weights + bias + residual -----------
__global__ __launch_bounds__(256) void agg1_kernel(
    const ushort* __restrict__ h1,   // [N,128] bf16
    const float* __restrict__ ss, const float* __restrict__ sd,  // [N]
    const int* __restrict__ rowptr, const unsigned* __restrict__ csrSD,
    const float* __restrict__ b1, const float2* __restrict__ x,
    float2* __restrict__ out) {
  const int n = blockIdx.x * 4 + (threadIdx.x >> 6);
  const int t = threadIdx.x & 63;
  const float sdn = sd[n];
  float a0 = 0.f, a1 = 0.f, den = 0.f;
  int p = rowptr[n];
  const int p1 = rowptr[n + 1];
  for (; p + 4 <= p1; p += 4) {
    int s[4];
#pragma unroll
    for (int j = 0; j < 4; ++j) s[j] = (int)(csrSD[p + j] & 0xFFFFu);
    ushort2 v[4];
#pragma unroll
    for (int j = 0; j < 4; ++j)
      v[j] = *reinterpret_cast<const ushort2*>(&h1[(size_t)s[j] * 128 + t * 2]);
    float w[4];
#pragma unroll
    for (int j = 0; j < 4; ++j) {
      float e = ss[s[j]] + sdn;
      e = (e > 0.f) ? e : NEG_SLOPE * e;
      w[j] = __expf(e);
    }
#pragma unroll
    for (int j = 0; j < 4; ++j) {
      den += w[j];
      a0 = fmaf(w[j], bf2f(v[j].x), a0);
      a1 = fmaf(w[j], bf2f(v[j].y), a1);
    }
  }
  for (; p < p1; ++p) {
    const int sj = (int)(csrSD[p] & 0xFFFFu);
    float e = ss[sj] + sdn;
    e = (e > 0.f) ? e : NEG_SLOPE * e;
    const float wj = __expf(e);
    const ushort2 vj = *reinterpret_cast<const ushort2*>(&h1[(size_t)sj * 128 + t * 2]);
    den += wj;
    a0 = fmaf(wj, bf2f(vj.x), a0);
    a1 = fmaf(wj, bf2f(vj.y), a1);
  }
  const float inv = 1.f / den;
  const float2 bv = reinterpret_cast<const float2*>(b1)[t];
  const float2 xv = x[(size_t)n * 64 + t];
  out[(size_t)n * 64 + t] =
      make_float2(xv.x + fmaf(a0, inv, bv.x), xv.y + fmaf(a1, inv, bv.y));
}

extern "C" void kernel_launch(void* const* d_in, const int* in_sizes, int n_in,
                              void* d_out, int out_size, void* d_ws, size_t ws_size,
                              hipStream_t stream) {
  const float* x      = (const float*)d_in[0];
  const float* W0     = (const float*)d_in[1];
  const float* a_src0 = (const float*)d_in[2];
  const float* a_dst0 = (const float*)d_in[3];
  const float* b0     = (const float*)d_in[4];
  const float* W1     = (const float*)d_in[5];
  const float* a_src1 = (const float*)d_in[6];
  const float* a_dst1 = (const float*)d_in[7];
  const float* b1     = (const float*)d_in[8];
  const int*   ei     = (const int*)d_in[9];
  const int E = in_sizes[9] / 2;
  const int Etot = E + N_NODES;
  float* out = (float*)d_out;
  (void)n_in; (void)out_size; (void)ws_size;

  char* ws = (char*)d_ws;
  size_t off = 0;
  auto alloc = [&](size_t bytes) -> char* {
    char* p = ws + off;
    off += (bytes + 255) & ~(size_t)255;
    return p;
  };
  ushort* h0b  = (ushort*)alloc((size_t)N_NODES * 256 * 2);
  ushort* hEb  = (ushort*)alloc((size_t)N_NODES * 256 * 2);
  ushort* h1b  = (ushort*)alloc((size_t)N_NODES * 128 * 2);
  ushort* W0T  = (ushort*)alloc((size_t)256 * 128 * 2);
  ushort* W1T  = (ushort*)alloc((size_t)128 * 256 * 2);
  int* counts  = (int*)alloc((size_t)N_NODES * 4);      // zero-init below
  float* ss0   = (float*)alloc((size_t)N_NODES * 2 * 4);  // direct-stored
  float* sd0   = (float*)alloc((size_t)N_NODES * 2 * 4);
  float* ss1   = (float*)alloc((size_t)N_NODES * 4);
  float* sd1   = (float*)alloc((size_t)N_NODES * 4);
  int* rowptr  = (int*)alloc((size_t)(N_NODES + 1) * 4);
  int* partial = (int*)alloc((size_t)N_NODES * 4);
  int* bsums   = (int*)alloc((size_t)64 * 4);
  ushort* rank = (ushort*)alloc((size_t)Etot * 2);
  unsigned* csrSD = (unsigned*)alloc((size_t)Etot * 4);

  hipMemsetAsync(counts, 0, (size_t)N_NODES * 4, stream);

  // ---- prep: weight transposes (one kernel) ----
  convT2_kernel<<<65536 / 256, 256, 0, stream>>>(W0, W0T, W1, W1T);

  // ---- CSR build, phase 1: hist + scans (scatter fused below) ----
  const int nblk = (N_NODES + 1023) / 1024;  // 49
  hist_kernel<<<(Etot + 255) / 256, 256, 0, stream>>>(ei, E, Etot, counts, rank);
  scan1_kernel<<<nblk, 1024, 0, stream>>>(counts, partial, bsums, N_NODES);
  scan23_kernel<<<(N_NODES + 255) / 256, 256, 0, stream>>>(partial, bsums, rowptr,
                                                           N_NODES, nblk);

  // ---- FUSED: layer-0 gemm (1564 blocks) + scatter (nS blocks) ----
  const int nS = (Etot + 255) / 256;
  const int grid = 3 * NG0 + ((nS > 2 * NG0) ? (nS - 2 * NG0) : 0);
  gemm0_scatter_kernel<<<grid, 256, 0, stream>>>(
      x, W0T, h0b, N_NODES, a_src0, a_dst0, ss0, sd0,
      ei, E, Etot, nS, rowptr, rank, csrSD);

  agg0_kernel<<<N_NODES / 4, 256, 0, stream>>>(h0b, ss0, sd0, rowptr, csrSD, b0, hEb);

  // ---- layer 1 ----
  dim3 g1(1, (N_NODES + 63) / 64);
  gemm_mfma<1, false><<<g1, 256, 0, stream>>>(hEb, W1T, h1b, N_NODES, 128, 256,
                                              a_src1, a_dst1, ss1, sd1);
  agg1_kernel<<<N_NODES / 4, 256, 0, stream>>>(h1b, ss1, sd1, rowptr, csrSD, b1,
                                               (const float2*)x, (float2*)out);
}

// Round 4
// 276.452 us; speedup vs baseline: 1.0266x; 1.0266x over previous
//
#include <hip/hip_runtime.h>

#define N_NODES 50000
#define NEG_SLOPE 0.2f

typedef short s8v __attribute__((ext_vector_type(8)));
typedef float f4v __attribute__((ext_vector_type(4)));

// ---- bf16 helpers (RNE) ---------------------------------------------------
__device__ __forceinline__ ushort f2bf(float f) {
  union { float f; unsigned u; } v; v.f = f;
  return (ushort)((v.u + 0x7FFFu + ((v.u >> 16) & 1u)) >> 16);
}
__device__ __forceinline__ float bf2f(ushort h) {
  union { unsigned u; float f; } v; v.u = ((unsigned)h) << 16;
  return v.f;
}

// ---- both weight transposes in one kernel ---------------------------------
__global__ void convT2_kernel(const float* __restrict__ W0, ushort* __restrict__ W0T,
                              const float* __restrict__ W1, ushort* __restrict__ W1T) {
  int i = blockIdx.x * blockDim.x + threadIdx.x;
  if (i < 32768) {
    int r = i >> 8, c = i & 255;           // W0: R=128, C=256
    W0T[c * 128 + r] = f2bf(W0[i]);
  } else {
    int j = i - 32768;
    int r = j >> 7, c = j & 127;           // W1: R=256, C=128
    W1T[c * 256 + r] = f2bf(W1[j]);
  }
}

// ---- MFMA GEMM, 64M x 128N tile + direct-store attention scores -----------
// R8/R10-proven structure — DO NOT restructure (R9's rewrite was flaky).
template <int HEADS, bool AF32>
__global__ __launch_bounds__(256) void gemm_mfma(
    const void* __restrict__ Av, const ushort* __restrict__ BT,
    ushort* __restrict__ C, int M, int N, int K,
    const float* __restrict__ a_src, const float* __restrict__ a_dst,
    float* __restrict__ ss, float* __restrict__ sd) {
  __shared__ ushort As[64][136];   // +8 pad: 16B-aligned, 2-way banks (free)
  __shared__ ushort Bs[128][136];
  const int tid = threadIdx.x;
  const int w = tid >> 6, lane = tid & 63;
  const int q = lane >> 4, r16 = lane & 15;
  const int n0 = blockIdx.x * 128, m0 = blockIdx.y * 64;
  f4v acc[8] = {};
  for (int kc = 0; kc < K; kc += 128) {
#pragma unroll
    for (int i = 0; i < 4; ++i) {
      int c = tid + 256 * i;
      int row = c >> 4, ko = (c & 15) * 8;
      int gm = m0 + row;
      s8v va = {};
      if (gm < M) {
        if (AF32) {
          const float* A = (const float*)Av;
          float4 f0 = *reinterpret_cast<const float4*>(&A[(size_t)gm * K + kc + ko]);
          float4 f1 = *reinterpret_cast<const float4*>(&A[(size_t)gm * K + kc + ko + 4]);
          va[0] = (short)f2bf(f0.x); va[1] = (short)f2bf(f0.y);
          va[2] = (short)f2bf(f0.z); va[3] = (short)f2bf(f0.w);
          va[4] = (short)f2bf(f1.x); va[5] = (short)f2bf(f1.y);
          va[6] = (short)f2bf(f1.z); va[7] = (short)f2bf(f1.w);
        } else {
          const ushort* A = (const ushort*)Av;
          va = *reinterpret_cast<const s8v*>(&A[(size_t)gm * K + kc + ko]);
        }
      }
      *reinterpret_cast<s8v*>(&As[row][ko]) = va;
    }
#pragma unroll
    for (int i = 0; i < 8; ++i) {
      int c = tid + 256 * i;
      int row = c >> 4, ko = (c & 15) * 8;
      s8v vb = *reinterpret_cast<const s8v*>(&BT[(size_t)(n0 + row) * K + kc + ko]);
      *reinterpret_cast<s8v*>(&Bs[row][ko]) = vb;
    }
    __syncthreads();
#pragma unroll
    for (int ks = 0; ks < 4; ++ks) {
      s8v af = *reinterpret_cast<const s8v*>(&As[w * 16 + r16][ks * 32 + q * 8]);
#pragma unroll
      for (int nt = 0; nt < 8; ++nt) {
        s8v bf = *reinterpret_cast<const s8v*>(&Bs[nt * 16 + r16][ks * 32 + q * 8]);
        acc[nt] = __builtin_amdgcn_mfma_f32_16x16x32_bf16(af, bf, acc[nt], 0, 0, 0);
      }
    }
    __syncthreads();
  }
#pragma unroll
  for (int nt = 0; nt < 8; ++nt)
#pragma unroll
    for (int r = 0; r < 4; ++r) {
      int gm = m0 + w * 16 + q * 4 + r;
      if (gm < M) C[(size_t)gm * N + n0 + nt * 16 + r16] = f2bf(acc[nt][r]);
    }
  const int head = n0 >> 7;
  float ps[4] = {0.f, 0.f, 0.f, 0.f}, pd[4] = {0.f, 0.f, 0.f, 0.f};
#pragma unroll
  for (int nt = 0; nt < 8; ++nt) {
    int n = n0 + nt * 16 + r16;
    float as = a_src[n], ad = a_dst[n];
#pragma unroll
    for (int r = 0; r < 4; ++r) {
      ps[r] = fmaf(acc[nt][r], as, ps[r]);
      pd[r] = fmaf(acc[nt][r], ad, pd[r]);
    }
  }
#pragma unroll
  for (int off = 1; off < 16; off <<= 1) {
#pragma unroll
    for (int r = 0; r < 4; ++r) {
      ps[r] += __shfl_xor(ps[r], off);
      pd[r] += __shfl_xor(pd[r], off);
    }
  }
  if (r16 == 0) {
#pragma unroll
    for (int r = 0; r < 4; ++r) {
      int gm = m0 + w * 16 + q * 4 + r;
      if (gm < M) {
        ss[gm * HEADS + head] = ps[r];
        sd[gm * HEADS + head] = pd[r];
      }
    }
  }
}

// ---- FUSED: layer-0 GEMM + CSR scatter in one dispatch --------------------
// gemm blocks (1564) and scatter blocks (nS) are INDEPENDENT (scatter's
// inputs rowptr/rank are complete before launch; gemm writes h0b/ss0/sd0).
// Interleave 1 gemm : 2 scatter in dispatch order for per-CU co-residency
// (MFMA pipe + memory pipe overlap; m114). gemm body verbatim from template.
#define NG0 1564  // 2 * ceil(N_NODES/64)
__global__ __launch_bounds__(256) void gemm0_scatter_kernel(
    const float* __restrict__ A, const ushort* __restrict__ BT,
    ushort* __restrict__ C, int M,
    const float* __restrict__ a_src, const float* __restrict__ a_dst,
    float* __restrict__ ss, float* __restrict__ sd,
    const int* __restrict__ ei, int E, int Etot, int nS,
    const int* __restrict__ rowptr, const ushort* __restrict__ rank,
    unsigned* __restrict__ csrSD) {
  __shared__ ushort As[64][136];
  __shared__ ushort Bs[128][136];
  const int id = blockIdx.x;
  int gemmIdx = -1, sIdx = -1;
  if (id < 3 * NG0) {
    const int g = id / 3, r = id % 3;
    if (r == 0) gemmIdx = g;
    else        sIdx = 2 * g + (r - 1);
  } else {
    sIdx = 2 * NG0 + (id - 3 * NG0);
  }

  if (gemmIdx >= 0) {
    // ---- gemm body (HEADS=2, AF32, N=256, K=128), x-major block order ----
    const int nb = gemmIdx & 1, mb = gemmIdx >> 1;
    const int tid = threadIdx.x;
    const int w = tid >> 6, lane = tid & 63;
    const int q = lane >> 4, r16 = lane & 15;
    const int n0 = nb * 128, m0 = mb * 64;
    const int N = 256, K = 128;
    f4v acc[8] = {};
    for (int kc = 0; kc < K; kc += 128) {
#pragma unroll
      for (int i = 0; i < 4; ++i) {
        int c = tid + 256 * i;
        int row = c >> 4, ko = (c & 15) * 8;
        int gm = m0 + row;
        s8v va = {};
        if (gm < M) {
          float4 f0 = *reinterpret_cast<const float4*>(&A[(size_t)gm * K + kc + ko]);
          float4 f1 = *reinterpret_cast<const float4*>(&A[(size_t)gm * K + kc + ko + 4]);
          va[0] = (short)f2bf(f0.x); va[1] = (short)f2bf(f0.y);
          va[2] = (short)f2bf(f0.z); va[3] = (short)f2bf(f0.w);
          va[4] = (short)f2bf(f1.x); va[5] = (short)f2bf(f1.y);
          va[6] = (short)f2bf(f1.z); va[7] = (short)f2bf(f1.w);
        }
        *reinterpret_cast<s8v*>(&As[row][ko]) = va;
      }
#pragma unroll
      for (int i = 0; i < 8; ++i) {
        int c = tid + 256 * i;
        int row = c >> 4, ko = (c & 15) * 8;
        s8v vb = *reinterpret_cast<const s8v*>(&BT[(size_t)(n0 + row) * K + kc + ko]);
        *reinterpret_cast<s8v*>(&Bs[row][ko]) = vb;
      }
      __syncthreads();
#pragma unroll
      for (int ks = 0; ks < 4; ++ks) {
        s8v af = *reinterpret_cast<const s8v*>(&As[w * 16 + r16][ks * 32 + q * 8]);
#pragma unroll
        for (int nt = 0; nt < 8; ++nt) {
          s8v bf = *reinterpret_cast<const s8v*>(&Bs[nt * 16 + r16][ks * 32 + q * 8]);
          acc[nt] = __builtin_amdgcn_mfma_f32_16x16x32_bf16(af, bf, acc[nt], 0, 0, 0);
        }
      }
      __syncthreads();
    }
#pragma unroll
    for (int nt = 0; nt < 8; ++nt)
#pragma unroll
      for (int r = 0; r < 4; ++r) {
        int gm = m0 + w * 16 + q * 4 + r;
        if (gm < M) C[(size_t)gm * N + n0 + nt * 16 + r16] = f2bf(acc[nt][r]);
      }
    const int head = n0 >> 7;
    float ps[4] = {0.f, 0.f, 0.f, 0.f}, pd[4] = {0.f, 0.f, 0.f, 0.f};
#pragma unroll
    for (int nt = 0; nt < 8; ++nt) {
      int n = n0 + nt * 16 + r16;
      float as = a_src[n], ad = a_dst[n];
#pragma unroll
      for (int r = 0; r < 4; ++r) {
        ps[r] = fmaf(acc[nt][r], as, ps[r]);
        pd[r] = fmaf(acc[nt][r], ad, pd[r]);
      }
    }
#pragma unroll
    for (int off = 1; off < 16; off <<= 1) {
#pragma unroll
      for (int r = 0; r < 4; ++r) {
        ps[r] += __shfl_xor(ps[r], off);
        pd[r] += __shfl_xor(pd[r], off);
      }
    }
    if (r16 == 0) {
#pragma unroll
      for (int r = 0; r < 4; ++r) {
        int gm = m0 + w * 16 + q * 4 + r;
        if (gm < M) {
          ss[gm * 2 + head] = ps[r];
          sd[gm * 2 + head] = pd[r];
        }
      }
    }
  } else {
    // ---- scatter body (verbatim from R12's scatter_kernel) ----
    if (sIdx >= nS) return;
    int e = sIdx * 256 + threadIdx.x;
    if (e >= Etot) return;
    int s, d;
    if (e < E) { s = ei[e]; d = ei[E + e]; } else { s = d = e - E; }
    csrSD[rowptr[d] + (int)rank[e]] = (unsigned)s | ((unsigned)d << 16);
  }
}

// ------------- CSR build: hist(+u16 rank) -> scan1 -> scan23 ---------------
__global__ void hist_kernel(const int* __restrict__ ei, int E, int Etot,
                            int* __restrict__ counts, ushort* __restrict__ rank) {
  int e = blockIdx.x * blockDim.x + threadIdx.x;
  if (e >= Etot) return;
  int d = (e < E) ? ei[E + e] : (e - E);
  rank[e] = (ushort)atomicAdd(&counts[d], 1);  // degree << 65536
}

__global__ __launch_bounds__(1024) void scan1_kernel(const int* __restrict__ counts,
                                                     int* __restrict__ partial,
                                                     int* __restrict__ blocksums, int n) {
  __shared__ int tmp[1024];
  int i = blockIdx.x * 1024 + threadIdx.x;
  int v = (i < n) ? counts[i] : 0;
  tmp[threadIdx.x] = v;
  __syncthreads();
  for (int off = 1; off < 1024; off <<= 1) {
    int t = (threadIdx.x >= off) ? tmp[threadIdx.x - off] : 0;
    __syncthreads();
    tmp[threadIdx.x] += t;
    __syncthreads();
  }
  if (i < n) partial[i] = tmp[threadIdx.x];
  if (threadIdx.x == 1023) blocksums[blockIdx.x] = tmp[1023];
}

__global__ void scan23_kernel(const int* __restrict__ partial,
                              const int* __restrict__ blocksums,
                              int* __restrict__ rowptr, int n, int nb) {
  __shared__ int sb[64];
  int t = threadIdx.x;
  if (t < 64) {
    int v = (t < nb) ? blocksums[t] : 0;
#pragma unroll
    for (int off = 1; off < 64; off <<= 1) {
      int u = __shfl_up(v, off);
      if ((t & 63) >= off) v += u;
    }
    sb[t] = v;
  }
  __syncthreads();
  int i = blockIdx.x * blockDim.x + t;
  if (i == 0) rowptr[0] = 0;
  if (i < n) {
    int b = i >> 10;
    int add = (b > 0) ? sb[b - 1] : 0;
    rowptr[i + 1] = partial[i] + add;
  }
}

// ---- layer-0 aggregation: whole-row wave, inline weights ------------------
// R13: 8 edges in flight (was 4). VGPR 24 -> ~44, still far below any
// occupancy cliff; doubles memory-level parallelism to attack the
// latency-bound regime (VALUBusy 54%, HBM 45%, neither saturated).
__global__ __launch_bounds__(256) void agg0_kernel(
    const ushort* __restrict__ h0,   // [N,256] bf16
    const float* __restrict__ ss, const float* __restrict__ sd,  // [N,2]
    const int* __restrict__ rowptr, const unsigned* __restrict__ csrSD,
    const float* __restrict__ b0, ushort* __restrict__ hE) {
  const int n = blockIdx.x * 4 + (threadIdx.x >> 6);
  const int t = threadIdx.x & 63;
  const int hd = t >> 5;
  const float sdn = sd[n * 2 + hd];
  float a0 = 0.f, a1 = 0.f, a2 = 0.f, a3 = 0.f, den = 0.f;
  int p = rowptr[n];
  const int p1 = rowptr[n + 1];
  for (; p + 8 <= p1; p += 8) {  // 8 rows in flight per wave
    int s[8];
#pragma unroll
    for (int j = 0; j < 8; ++j) s[j] = (int)(csrSD[p + j] & 0xFFFFu);
    ushort4 v[8];
#pragma unroll
    for (int j = 0; j < 8; ++j)
      v[j] = *reinterpret_cast<const ushort4*>(&h0[(size_t)s[j] * 256 + t * 4]);
    float w[8];
#pragma unroll
    for (int j = 0; j < 8; ++j) {
      float e = ss[s[j] * 2 + hd] + sdn;
      e = (e > 0.f) ? e : NEG_SLOPE * e;
      w[j] = __expf(e);
    }
#pragma unroll
    for (int j = 0; j < 8; ++j) {
      den += w[j];
      a0 = fmaf(w[j], bf2f(v[j].x), a0);
      a1 = fmaf(w[j], bf2f(v[j].y), a1);
      a2 = fmaf(w[j], bf2f(v[j].z), a2);
      a3 = fmaf(w[j], bf2f(v[j].w), a3);
    }
  }
  for (; p + 4 <= p1; p += 4) {
    int s[4];
#pragma unroll
    for (int j = 0; j < 4; ++j) s[j] = (int)(csrSD[p + j] & 0xFFFFu);
    ushort4 v[4];
#pragma unroll
    for (int j = 0; j < 4; ++j)
      v[j] = *reinterpret_cast<const ushort4*>(&h0[(size_t)s[j] * 256 + t * 4]);
    float w[4];
#pragma unroll
    for (int j = 0; j < 4; ++j) {
      float e = ss[s[j] * 2 + hd] + sdn;
      e = (e > 0.f) ? e : NEG_SLOPE * e;
      w[j] = __expf(e);
    }
#pragma unroll
    for (int j = 0; j < 4; ++j) {
      den += w[j];
      a0 = fmaf(w[j], bf2f(v[j].x), a0);
      a1 = fmaf(w[j], bf2f(v[j].y), a1);
      a2 = fmaf(w[j], bf2f(v[j].z), a2);
      a3 = fmaf(w[j], bf2f(v[j].w), a3);
    }
  }
  for (; p < p1; ++p) {
    const int sj = (int)(csrSD[p] & 0xFFFFu);
    float e = ss[sj * 2 + hd] + sdn;
    e = (e > 0.f) ? e : NEG_SLOPE * e;
    const float wj = __expf(e);
    const ushort4 vj = *reinterpret_cast<const ushort4*>(&h0[(size_t)sj * 256 + t * 4]);
    den += wj;
    a0 = fmaf(wj, bf2f(vj.x), a0); a1 = fmaf(wj, bf2f(vj.y), a1);
    a2 = fmaf(wj, bf2f(vj.z), a2); a3 = fmaf(wj, bf2f(vj.w), a3);
  }
  const float inv = 1.f / den;
  const float4 bv = reinterpret_cast<const float4*>(b0)[t];
  float o[4] = {fmaf(a0, inv, bv.x), fmaf(a1, inv, bv.y),
                fmaf(a2, inv, bv.z), fmaf(a3, inv, bv.w)};
#pragma unroll
  for (int i = 0; i < 4; ++i) o[i] = (o[i] > 0.f) ? o[i] : (__expf(o[i]) - 1.f);
  ushort4 ov; ov.x = f2bf(o[0]); ov.y = f2bf(o[1]); ov.z = f2bf(o[2]); ov.w = f2bf(o[3]);
  *reinterpret_cast<ushort4*>(&hE[(size_t)n * 256 + t * 4]) = ov;
}

// ---- layer-1 aggregation: inline edge weights + bias + residual -----------
// R13: 8 edges in flight (same latency-bound fix as agg0).
__global__ __launch_bounds__(256) void agg1_kernel(
    const ushort* __restrict__ h1,   // [N,128] bf16
    const float* __restrict__ ss, const float* __restrict__ sd,  // [N]
    const int* __restrict__ rowptr, const unsigned* __restrict__ csrSD,
    const float* __restrict__ b1, const float2* __restrict__ x,
    float2* __restrict__ out) {
  const int n = blockIdx.x * 4 + (threadIdx.x >> 6);
  const int t = threadIdx.x & 63;
  const float sdn = sd[n];
  float a0 = 0.f, a1 = 0.f, den = 0.f;
  int p = rowptr[n];
  const int p1 = rowptr[n + 1];
  for (; p + 8 <= p1; p += 8) {
    int s[8];
#pragma unroll
    for (int j = 0; j < 8; ++j) s[j] = (int)(csrSD[p + j] & 0xFFFFu);
    ushort2 v[8];
#pragma unroll
    for (int j = 0; j < 8; ++j)
      v[j] = *reinterpret_cast<const ushort2*>(&h1[(size_t)s[j] * 128 + t * 2]);
    float w[8];
#pragma unroll
    for (int j = 0; j < 8; ++j) {
      float e = ss[s[j]] + sdn;
      e = (e > 0.f) ? e : NEG_SLOPE * e;
      w[j] = __expf(e);
    }
#pragma unroll
    for (int j = 0; j < 8; ++j) {
      den += w[j];
      a0 = fmaf(w[j], bf2f(v[j].x), a0);
      a1 = fmaf(w[j], bf2f(v[j].y), a1);
    }
  }
  for (; p + 4 <= p1; p += 4) {
    int s[4];
#pragma unroll
    for (int j = 0; j < 4; ++j) s[j] = (int)(csrSD[p + j] & 0xFFFFu);
    ushort2 v[4];
#pragma unroll
    for (int j = 0; j < 4; ++j)
      v[j] = *reinterpret_cast<const ushort2*>(&h1[(size_t)s[j] * 128 + t * 2]);
    float w[4];
#pragma unroll
    for (int j = 0; j < 4; ++j) {
      float e = ss[s[j]] + sdn;
      e = (e > 0.f) ? e : NEG_SLOPE * e;
      w[j] = __expf(e);
    }
#pragma unroll
    for (int j = 0; j < 4; ++j) {
      den += w[j];
      a0 = fmaf(w[j], bf2f(v[j].x), a0);
      a1 = fmaf(w[j], bf2f(v[j].y), a1);
    }
  }
  for (; p < p1; ++p) {
    const int sj = (int)(csrSD[p] & 0xFFFFu);
    float e = ss[sj] + sdn;
    e = (e > 0.f) ? e : NEG_SLOPE * e;
    const float wj = __expf(e);
    const ushort2 vj = *reinterpret_cast<const ushort2*>(&h1[(size_t)sj * 128 + t * 2]);
    den += wj;
    a0 = fmaf(wj, bf2f(vj.x), a0);
    a1 = fmaf(wj, bf2f(vj.y), a1);
  }
  const float inv = 1.f / den;
  const float2 bv = reinterpret_cast<const float2*>(b1)[t];
  const float2 xv = x[(size_t)n * 64 + t];
  out[(size_t)n * 64 + t] =
      make_float2(xv.x + fmaf(a0, inv, bv.x), xv.y + fmaf(a1, inv, bv.y));
}

extern "C" void kernel_launch(void* const* d_in, const int* in_sizes, int n_in,
                              void* d_out, int out_size, void* d_ws, size_t ws_size,
                              hipStream_t stream) {
  const float* x      = (const float*)d_in[0];
  const float* W0     = (const float*)d_in[1];
  const float* a_src0 = (const float*)d_in[2];
  const float* a_dst0 = (const float*)d_in[3];
  const float* b0     = (const float*)d_in[4];
  const float* W1     = (const float*)d_in[5];
  const float* a_src1 = (const float*)d_in[6];
  const float* a_dst1 = (const float*)d_in[7];
  const float* b1     = (const float*)d_in[8];
  const int*   ei     = (const int*)d_in[9];
  const int E = in_sizes[9] / 2;
  const int Etot = E + N_NODES;
  float* out = (float*)d_out;
  (void)n_in; (void)out_size; (void)ws_size;

  char* ws = (char*)d_ws;
  size_t off = 0;
  auto alloc = [&](size_t bytes) -> char* {
    char* p = ws + off;
    off += (bytes + 255) & ~(size_t)255;
    return p;
  };
  ushort* h0b  = (ushort*)alloc((size_t)N_NODES * 256 * 2);
  ushort* hEb  = (ushort*)alloc((size_t)N_NODES * 256 * 2);
  ushort* h1b  = (ushort*)alloc((size_t)N_NODES * 128 * 2);
  ushort* W0T  = (ushort*)alloc((size_t)256 * 128 * 2);
  ushort* W1T  = (ushort*)alloc((size_t)128 * 256 * 2);
  int* counts  = (int*)alloc((size_t)N_NODES * 4);      // zero-init below
  float* ss0   = (float*)alloc((size_t)N_NODES * 2 * 4);  // direct-stored
  float* sd0   = (float*)alloc((size_t)N_NODES * 2 * 4);
  float* ss1   = (float*)alloc((size_t)N_NODES * 4);
  float* sd1   = (float*)alloc((size_t)N_NODES * 4);
  int* rowptr  = (int*)alloc((size_t)(N_NODES + 1) * 4);
  int* partial = (int*)alloc((size_t)N_NODES * 4);
  int* bsums   = (int*)alloc((size_t)64 * 4);
  ushort* rank = (ushort*)alloc((size_t)Etot * 2);
  unsigned* csrSD = (unsigned*)alloc((size_t)Etot * 4);

  hipMemsetAsync(counts, 0, (size_t)N_NODES * 4, stream);

  // ---- prep: weight transposes (one kernel) ----
  convT2_kernel<<<65536 / 256, 256, 0, stream>>>(W0, W0T, W1, W1T);

  // ---- CSR build, phase 1: hist + scans (scatter fused below) ----
  const int nblk = (N_NODES + 1023) / 1024;  // 49
  hist_kernel<<<(Etot + 255) / 256, 256, 0, stream>>>(ei, E, Etot, counts, rank);
  scan1_kernel<<<nblk, 1024, 0, stream>>>(counts, partial, bsums, N_NODES);
  scan23_kernel<<<(N_NODES + 255) / 256, 256, 0, stream>>>(partial, bsums, rowptr,
                                                           N_NODES, nblk);

  // ---- FUSED: layer-0 gemm (1564 blocks) + scatter (nS blocks) ----
  const int nS = (Etot + 255) / 256;
  const int grid = 3 * NG0 + ((nS > 2 * NG0) ? (nS - 2 * NG0) : 0);
  gemm0_scatter_kernel<<<grid, 256, 0, stream>>>(
      x, W0T, h0b, N_NODES, a_src0, a_dst0, ss0, sd0,
      ei, E, Etot, nS, rowptr, rank, csrSD);

  agg0_kernel<<<N_NODES / 4, 256, 0, stream>>>(h0b, ss0, sd0, rowptr, csrSD, b0, hEb);

  // ---- layer 1 ----
  dim3 g1(1, (N_NODES + 63) / 64);
  gemm_mfma<1, false><<<g1, 256, 0, stream>>>(hEb, W1T, h1b, N_NODES, 128, 256,
                                              a_src1, a_dst1, ss1, sd1);
  agg1_kernel<<<N_NODES / 4, 256, 0, stream>>>(h1b, ss1, sd1, rowptr, csrSD, b1,
                                               (const float2*)x, (float2*)out);
}

// Round 7
// 271.997 us; speedup vs baseline: 1.0434x; 1.0164x over previous
//
#include <hip/hip_runtime.h>

#define N_NODES 50000
#define NEG_SLOPE 0.2f

typedef short s8v __attribute__((ext_vector_type(8)));
typedef float f4v __attribute__((ext_vector_type(4)));

// ---- bf16 helpers (RNE) ---------------------------------------------------
__device__ __forceinline__ ushort f2bf(float f) {
  union { float f; unsigned u; } v; v.f = f;
  return (ushort)((v.u + 0x7FFFu + ((v.u >> 16) & 1u)) >> 16);
}
__device__ __forceinline__ float bf2f(ushort h) {
  union { unsigned u; float f; } v; v.u = ((unsigned)h) << 16;
  return v.f;
}

// ---- both weight transposes in one kernel ---------------------------------
__global__ void convT2_kernel(const float* __restrict__ W0, ushort* __restrict__ W0T,
                              const float* __restrict__ W1, ushort* __restrict__ W1T) {
  int i = blockIdx.x * blockDim.x + threadIdx.x;
  if (i < 32768) {
    int r = i >> 8, c = i & 255;           // W0: R=128, C=256
    W0T[c * 128 + r] = f2bf(W0[i]);
  } else {
    int j = i - 32768;
    int r = j >> 7, c = j & 127;           // W1: R=256, C=128
    W1T[c * 256 + r] = f2bf(W1[j]);
  }
}

// ---- MFMA GEMM, 64M x 128N tile + direct-store attention scores -----------
// R8/R10-proven structure — DO NOT restructure (R9's rewrite was flaky).
template <int HEADS, bool AF32>
__global__ __launch_bounds__(256) void gemm_mfma(
    const void* __restrict__ Av, const ushort* __restrict__ BT,
    ushort* __restrict__ C, int M, int N, int K,
    const float* __restrict__ a_src, const float* __restrict__ a_dst,
    float* __restrict__ ss, float* __restrict__ sd) {
  __shared__ ushort As[64][136];   // +8 pad: 16B-aligned, 2-way banks (free)
  __shared__ ushort Bs[128][136];
  const int tid = threadIdx.x;
  const int w = tid >> 6, lane = tid & 63;
  const int q = lane >> 4, r16 = lane & 15;
  const int n0 = blockIdx.x * 128, m0 = blockIdx.y * 64;
  f4v acc[8] = {};
  for (int kc = 0; kc < K; kc += 128) {
#pragma unroll
    for (int i = 0; i < 4; ++i) {
      int c = tid + 256 * i;
      int row = c >> 4, ko = (c & 15) * 8;
      int gm = m0 + row;
      s8v va = {};
      if (gm < M) {
        if (AF32) {
          const float* A = (const float*)Av;
          float4 f0 = *reinterpret_cast<const float4*>(&A[(size_t)gm * K + kc + ko]);
          float4 f1 = *reinterpret_cast<const float4*>(&A[(size_t)gm * K + kc + ko + 4]);
          va[0] = (short)f2bf(f0.x); va[1] = (short)f2bf(f0.y);
          va[2] = (short)f2bf(f0.z); va[3] = (short)f2bf(f0.w);
          va[4] = (short)f2bf(f1.x); va[5] = (short)f2bf(f1.y);
          va[6] = (short)f2bf(f1.z); va[7] = (short)f2bf(f1.w);
        } else {
          const ushort* A = (const ushort*)Av;
          va = *reinterpret_cast<const s8v*>(&A[(size_t)gm * K + kc + ko]);
        }
      }
      *reinterpret_cast<s8v*>(&As[row][ko]) = va;
    }
#pragma unroll
    for (int i = 0; i < 8; ++i) {
      int c = tid + 256 * i;
      int row = c >> 4, ko = (c & 15) * 8;
      s8v vb = *reinterpret_cast<const s8v*>(&BT[(size_t)(n0 + row) * K + kc + ko]);
      *reinterpret_cast<s8v*>(&Bs[row][ko]) = vb;
    }
    __syncthreads();
#pragma unroll
    for (int ks = 0; ks < 4; ++ks) {
      s8v af = *reinterpret_cast<const s8v*>(&As[w * 16 + r16][ks * 32 + q * 8]);
#pragma unroll
      for (int nt = 0; nt < 8; ++nt) {
        s8v bf = *reinterpret_cast<const s8v*>(&Bs[nt * 16 + r16][ks * 32 + q * 8]);
        acc[nt] = __builtin_amdgcn_mfma_f32_16x16x32_bf16(af, bf, acc[nt], 0, 0, 0);
      }
    }
    __syncthreads();
  }
#pragma unroll
  for (int nt = 0; nt < 8; ++nt)
#pragma unroll
    for (int r = 0; r < 4; ++r) {
      int gm = m0 + w * 16 + q * 4 + r;
      if (gm < M) C[(size_t)gm * N + n0 + nt * 16 + r16] = f2bf(acc[nt][r]);
    }
  const int head = n0 >> 7;
  float ps[4] = {0.f, 0.f, 0.f, 0.f}, pd[4] = {0.f, 0.f, 0.f, 0.f};
#pragma unroll
  for (int nt = 0; nt < 8; ++nt) {
    int n = n0 + nt * 16 + r16;
    float as = a_src[n], ad = a_dst[n];
#pragma unroll
    for (int r = 0; r < 4; ++r) {
      ps[r] = fmaf(acc[nt][r], as, ps[r]);
      pd[r] = fmaf(acc[nt][r], ad, pd[r]);
    }
  }
#pragma unroll
  for (int off = 1; off < 16; off <<= 1) {
#pragma unroll
    for (int r = 0; r < 4; ++r) {
      ps[r] += __shfl_xor(ps[r], off);
      pd[r] += __shfl_xor(pd[r], off);
    }
  }
  if (r16 == 0) {
#pragma unroll
    for (int r = 0; r < 4; ++r) {
      int gm = m0 + w * 16 + q * 4 + r;
      if (gm < M) {
        ss[gm * HEADS + head] = ps[r];
        sd[gm * HEADS + head] = pd[r];
      }
    }
  }
}

// ---- FUSED: layer-0 GEMM + CSR scatter in one dispatch --------------------
// gemm blocks (1564) and scatter blocks (nS) are INDEPENDENT (scatter's
// inputs rowptr/rank are complete before launch; gemm writes h0b/ss0/sd0).
// Interleave 1 gemm : 2 scatter in dispatch order for per-CU co-residency
// (MFMA pipe + memory pipe overlap; m114). gemm body verbatim from template.
#define NG0 1564  // 2 * ceil(N_NODES/64)
__global__ __launch_bounds__(256) void gemm0_scatter_kernel(
    const float* __restrict__ A, const ushort* __restrict__ BT,
    ushort* __restrict__ C, int M,
    const float* __restrict__ a_src, const float* __restrict__ a_dst,
    float* __restrict__ ss, float* __restrict__ sd,
    const int* __restrict__ ei, int E, int Etot, int nS,
    const int* __restrict__ rowptr, const ushort* __restrict__ rank,
    unsigned* __restrict__ csrSD) {
  __shared__ ushort As[64][136];
  __shared__ ushort Bs[128][136];
  const int id = blockIdx.x;
  int gemmIdx = -1, sIdx = -1;
  if (id < 3 * NG0) {
    const int g = id / 3, r = id % 3;
    if (r == 0) gemmIdx = g;
    else        sIdx = 2 * g + (r - 1);
  } else {
    sIdx = 2 * NG0 + (id - 3 * NG0);
  }

  if (gemmIdx >= 0) {
    // ---- gemm body (HEADS=2, AF32, N=256, K=128), x-major block order ----
    const int nb = gemmIdx & 1, mb = gemmIdx >> 1;
    const int tid = threadIdx.x;
    const int w = tid >> 6, lane = tid & 63;
    const int q = lane >> 4, r16 = lane & 15;
    const int n0 = nb * 128, m0 = mb * 64;
    const int N = 256, K = 128;
    f4v acc[8] = {};
    for (int kc = 0; kc < K; kc += 128) {
#pragma unroll
      for (int i = 0; i < 4; ++i) {
        int c = tid + 256 * i;
        int row = c >> 4, ko = (c & 15) * 8;
        int gm = m0 + row;
        s8v va = {};
        if (gm < M) {
          float4 f0 = *reinterpret_cast<const float4*>(&A[(size_t)gm * K + kc + ko]);
          float4 f1 = *reinterpret_cast<const float4*>(&A[(size_t)gm * K + kc + ko + 4]);
          va[0] = (short)f2bf(f0.x); va[1] = (short)f2bf(f0.y);
          va[2] = (short)f2bf(f0.z); va[3] = (short)f2bf(f0.w);
          va[4] = (short)f2bf(f1.x); va[5] = (short)f2bf(f1.y);
          va[6] = (short)f2bf(f1.z); va[7] = (short)f2bf(f1.w);
        }
        *reinterpret_cast<s8v*>(&As[row][ko]) = va;
      }
#pragma unroll
      for (int i = 0; i < 8; ++i) {
        int c = tid + 256 * i;
        int row = c >> 4, ko = (c & 15) * 8;
        s8v vb = *reinterpret_cast<const s8v*>(&BT[(size_t)(n0 + row) * K + kc + ko]);
        *reinterpret_cast<s8v*>(&Bs[row][ko]) = vb;
      }
      __syncthreads();
#pragma unroll
      for (int ks = 0; ks < 4; ++ks) {
        s8v af = *reinterpret_cast<const s8v*>(&As[w * 16 + r16][ks * 32 + q * 8]);
#pragma unroll
        for (int nt = 0; nt < 8; ++nt) {
          s8v bf = *reinterpret_cast<const s8v*>(&Bs[nt * 16 + r16][ks * 32 + q * 8]);
          acc[nt] = __builtin_amdgcn_mfma_f32_16x16x32_bf16(af, bf, acc[nt], 0, 0, 0);
        }
      }
      __syncthreads();
    }
#pragma unroll
    for (int nt = 0; nt < 8; ++nt)
#pragma unroll
      for (int r = 0; r < 4; ++r) {
        int gm = m0 + w * 16 + q * 4 + r;
        if (gm < M) C[(size_t)gm * N + n0 + nt * 16 + r16] = f2bf(acc[nt][r]);
      }
    const int head = n0 >> 7;
    float ps[4] = {0.f, 0.f, 0.f, 0.f}, pd[4] = {0.f, 0.f, 0.f, 0.f};
#pragma unroll
    for (int nt = 0; nt < 8; ++nt) {
      int n = n0 + nt * 16 + r16;
      float as = a_src[n], ad = a_dst[n];
#pragma unroll
      for (int r = 0; r < 4; ++r) {
        ps[r] = fmaf(acc[nt][r], as, ps[r]);
        pd[r] = fmaf(acc[nt][r], ad, pd[r]);
      }
    }
#pragma unroll
    for (int off = 1; off < 16; off <<= 1) {
#pragma unroll
      for (int r = 0; r < 4; ++r) {
        ps[r] += __shfl_xor(ps[r], off);
        pd[r] += __shfl_xor(pd[r], off);
      }
    }
    if (r16 == 0) {
#pragma unroll
      for (int r = 0; r < 4; ++r) {
        int gm = m0 + w * 16 + q * 4 + r;
        if (gm < M) {
          ss[gm * 2 + head] = ps[r];
          sd[gm * 2 + head] = pd[r];
        }
      }
    }
  } else {
    // ---- scatter body (verbatim from R12's scatter_kernel) ----
    if (sIdx >= nS) return;
    int e = sIdx * 256 + threadIdx.x;
    if (e >= Etot) return;
    int s, d;
    if (e < E) { s = ei[e]; d = ei[E + e]; } else { s = d = e - E; }
    csrSD[rowptr[d] + (int)rank[e]] = (unsigned)s | ((unsigned)d << 16);
  }
}

// ------------- CSR build: hist(+u16 rank) -> scan1 -> scan23 ---------------
__global__ void hist_kernel(const int* __restrict__ ei, int E, int Etot,
                            int* __restrict__ counts, ushort* __restrict__ rank) {
  int e = blockIdx.x * blockDim.x + threadIdx.x;
  if (e >= Etot) return;
  int d = (e < E) ? ei[E + e] : (e - E);
  rank[e] = (ushort)atomicAdd(&counts[d], 1);  // degree << 65536
}

__global__ __launch_bounds__(1024) void scan1_kernel(const int* __restrict__ counts,
                                                     int* __restrict__ partial,
                                                     int* __restrict__ blocksums, int n) {
  __shared__ int tmp[1024];
  int i = blockIdx.x * 1024 + threadIdx.x;
  int v = (i < n) ? counts[i] : 0;
  tmp[threadIdx.x] = v;
  __syncthreads();
  for (int off = 1; off < 1024; off <<= 1) {
    int t = (threadIdx.x >= off) ? tmp[threadIdx.x - off] : 0;
    __syncthreads();
    tmp[threadIdx.x] += t;
    __syncthreads();
  }
  if (i < n) partial[i] = tmp[threadIdx.x];
  if (threadIdx.x == 1023) blocksums[blockIdx.x] = tmp[1023];
}

__global__ void scan23_kernel(const int* __restrict__ partial,
                              const int* __restrict__ blocksums,
                              int* __restrict__ rowptr, int n, int nb) {
  __shared__ int sb[64];
  int t = threadIdx.x;
  if (t < 64) {
    int v = (t < nb) ? blocksums[t] : 0;
#pragma unroll
    for (int off = 1; off < 64; off <<= 1) {
      int u = __shfl_up(v, off);
      if ((t & 63) >= off) v += u;
    }
    sb[t] = v;
  }
  __syncthreads();
  int i = blockIdx.x * blockDim.x + t;
  if (i == 0) rowptr[0] = 0;
  if (i < n) {
    int b = i >> 10;
    int add = (b > 0) ? sb[b - 1] : 0;
    rowptr[i + 1] = partial[i] + add;
  }
}

// ---- layer-0 aggregation: whole-row wave, SGPR-scalarized (R14) -----------
// R14 theory: VALUBusy*dur ≈ 34 µs ⇒ ~40 VALU/edge/lane, mostly redundant
// wave-uniform address math (n, p, csrSD, s[j], row bases, ss addr).
// readfirstlane forces them to SGPRs: gather = SGPR base + invariant voffset
// (zero per-edge VALU addr math); csrSD/ss/rowptr/sd leave the VMEM path.
__global__ __launch_bounds__(256) void agg0_kernel(
    const ushort* __restrict__ h0,   // [N,256] bf16
    const float* __restrict__ ss, const float* __restrict__ sd,  // [N,2]
    const int* __restrict__ rowptr, const unsigned* __restrict__ csrSD,
    const float* __restrict__ b0, ushort* __restrict__ hE) {
  const int n = __builtin_amdgcn_readfirstlane(blockIdx.x * 4 + (threadIdx.x >> 6));
  const int t = threadIdx.x & 63;
  const int hd = t >> 5;
  const float2 sdv = *reinterpret_cast<const float2*>(&sd[n * 2]);
  const float sdn = hd ? sdv.y : sdv.x;
  float a0 = 0.f, a1 = 0.f, a2 = 0.f, a3 = 0.f, den = 0.f;
  int p = __builtin_amdgcn_readfirstlane(rowptr[n]);
  const int p1 = __builtin_amdgcn_readfirstlane(rowptr[n + 1]);
  for (; p + 8 <= p1; p += 8) {  // 8 rows in flight per wave
    int s[8];
#pragma unroll
    for (int j = 0; j < 8; ++j)
      s[j] = __builtin_amdgcn_readfirstlane((int)(csrSD[p + j] & 0xFFFFu));
    ushort4 v[8];
#pragma unroll
    for (int j = 0; j < 8; ++j) {
      const ushort* row = h0 + (size_t)s[j] * 256;   // SGPR base
      v[j] = *reinterpret_cast<const ushort4*>(row + t * 4);
    }
    float w[8];
#pragma unroll
    for (int j = 0; j < 8; ++j) {
      const float2 sv = *reinterpret_cast<const float2*>(&ss[s[j] * 2]);
      float e = (hd ? sv.y : sv.x) + sdn;
      e = (e > 0.f) ? e : NEG_SLOPE * e;
      w[j] = __expf(e);
    }
#pragma unroll
    for (int j = 0; j < 8; ++j) {
      den += w[j];
      a0 = fmaf(w[j], bf2f(v[j].x), a0);
      a1 = fmaf(w[j], bf2f(v[j].y), a1);
      a2 = fmaf(w[j], bf2f(v[j].z), a2);
      a3 = fmaf(w[j], bf2f(v[j].w), a3);
    }
  }
  for (; p + 4 <= p1; p += 4) {
    int s[4];
#pragma unroll
    for (int j = 0; j < 4; ++j)
      s[j] = __builtin_amdgcn_readfirstlane((int)(csrSD[p + j] & 0xFFFFu));
    ushort4 v[4];
#pragma unroll
    for (int j = 0; j < 4; ++j) {
      const ushort* row = h0 + (size_t)s[j] * 256;
      v[j] = *reinterpret_cast<const ushort4*>(row + t * 4);
    }
    float w[4];
#pragma unroll
    for (int j = 0; j < 4; ++j) {
      const float2 sv = *reinterpret_cast<const float2*>(&ss[s[j] * 2]);
      float e = (hd ? sv.y : sv.x) + sdn;
      e = (e > 0.f) ? e : NEG_SLOPE * e;
      w[j] = __expf(e);
    }
#pragma unroll
    for (int j = 0; j < 4; ++j) {
      den += w[j];
      a0 = fmaf(w[j], bf2f(v[j].x), a0);
      a1 = fmaf(w[j], bf2f(v[j].y), a1);
      a2 = fmaf(w[j], bf2f(v[j].z), a2);
      a3 = fmaf(w[j], bf2f(v[j].w), a3);
    }
  }
  for (; p < p1; ++p) {
    const int sj = __builtin_amdgcn_readfirstlane((int)(csrSD[p] & 0xFFFFu));
    const float2 sv = *reinterpret_cast<const float2*>(&ss[sj * 2]);
    float e = (hd ? sv.y : sv.x) + sdn;
    e = (e > 0.f) ? e : NEG_SLOPE * e;
    const float wj = __expf(e);
    const ushort* row = h0 + (size_t)sj * 256;
    const ushort4 vj = *reinterpret_cast<const ushort4*>(row + t * 4);
    den += wj;
    a0 = fmaf(wj, bf2f(vj.x), a0); a1 = fmaf(wj, bf2f(vj.y), a1);
    a2 = fmaf(wj, bf2f(vj.z), a2); a3 = fmaf(wj, bf2f(vj.w), a3);
  }
  const float inv = 1.f / den;
  const float4 bv = reinterpret_cast<const float4*>(b0)[t];
  float o[4] = {fmaf(a0, inv, bv.x), fmaf(a1, inv, bv.y),
                fmaf(a2, inv, bv.z), fmaf(a3, inv, bv.w)};
#pragma unroll
  for (int i = 0; i < 4; ++i) o[i] = (o[i] > 0.f) ? o[i] : (__expf(o[i]) - 1.f);
  ushort4 ov; ov.x = f2bf(o[0]); ov.y = f2bf(o[1]); ov.z = f2bf(o[2]); ov.w = f2bf(o[3]);
  *reinterpret_cast<ushort4*>(&hE[(size_t)n * 256 + t * 4]) = ov;
}

// ---- layer-1 aggregation: SGPR-scalarized (R14, same as agg0) -------------
__global__ __launch_bounds__(256) void agg1_kernel(
    const ushort* __restrict__ h1,   // [N,128] bf16
    const float* __restrict__ ss, const float* __restrict__ sd,  // [N]
    const int* __restrict__ rowptr, const unsigned* __restrict__ csrSD,
    const float* __restrict__ b1, const float2* __restrict__ x,
    float2* __restrict__ out) {
  const int n = __builtin_amdgcn_readfirstlane(blockIdx.x * 4 + (threadIdx.x >> 6));
  const int t = threadIdx.x & 63;
  const float sdn = sd[n];
  float a0 = 0.f, a1 = 0.f, den = 0.f;
  int p = __builtin_amdgcn_readfirstlane(rowptr[n]);
  const int p1 = __builtin_amdgcn_readfirstlane(rowptr[n + 1]);
  for (; p + 8 <= p1; p += 8) {
    int s[8];
#pragma unroll
    for (int j = 0; j < 8; ++j)
      s[j] = __builtin_amdgcn_readfirstlane((int)(csrSD[p + j] & 0xFFFFu));
    ushort2 v[8];
#pragma unroll
    for (int j = 0; j < 8; ++j) {
      const ushort* row = h1 + (size_t)s[j] * 128;
      v[j] = *reinterpret_cast<const ushort2*>(row + t * 2);
    }
    float w[8];
#pragma unroll
    for (int j = 0; j < 8; ++j) {
      float e = ss[s[j]] + sdn;
      e = (e > 0.f) ? e : NEG_SLOPE * e;
      w[j] = __expf(e);
    }
#pragma unroll
    for (int j = 0; j < 8; ++j) {
      den += w[j];
      a0 = fmaf(w[j], bf2f(v[j].x), a0);
      a1 = fmaf(w[j], bf2f(v[j].y), a1);
    }
  }
  for (; p + 4 <= p1; p += 4) {
    int s[4];
#pragma unroll
    for (int j = 0; j < 4; ++j)
      s[j] = __builtin_amdgcn_readfirstlane((int)(csrSD[p + j] & 0xFFFFu));
    ushort2 v[4];
#pragma unroll
    for (int j = 0; j < 4; ++j) {
      const ushort* row = h1 + (size_t)s[j] * 128;
      v[j] = *reinterpret_cast<const ushort2*>(row + t * 2);
    }
    float w[4];
#pragma unroll
    for (int j = 0; j < 4; ++j) {
      float e = ss[s[j]] + sdn;
      e = (e > 0.f) ? e : NEG_SLOPE * e;
      w[j] = __expf(e);
    }
#pragma unroll
    for (int j = 0; j < 4; ++j) {
      den += w[j];
      a0 = fmaf(w[j], bf2f(v[j].x), a0);
      a1 = fmaf(w[j], bf2f(v[j].y), a1);
    }
  }
  for (; p < p1; ++p) {
    const int sj = __builtin_amdgcn_readfirstlane((int)(csrSD[p] & 0xFFFFu));
    float e = ss[sj] + sdn;
    e = (e > 0.f) ? e : NEG_SLOPE * e;
    const float wj = __expf(e);
    const ushort* row = h1 + (size_t)sj * 128;
    const ushort2 vj = *reinterpret_cast<const ushort2*>(row + t * 2);
    den += wj;
    a0 = fmaf(wj, bf2f(vj.x), a0);
    a1 = fmaf(wj, bf2f(vj.y), a1);
  }
  const float inv = 1.f / den;
  const float2 bv = reinterpret_cast<const float2*>(b1)[t];
  const float2 xv = x[(size_t)n * 64 + t];
  out[(size_t)n * 64 + t] =
      make_float2(xv.x + fmaf(a0, inv, bv.x), xv.y + fmaf(a1, inv, bv.y));
}

extern "C" void kernel_launch(void* const* d_in, const int* in_sizes, int n_in,
                              void* d_out, int out_size, void* d_ws, size_t ws_size,
                              hipStream_t stream) {
  const float* x      = (const float*)d_in[0];
  const float* W0     = (const float*)d_in[1];
  const float* a_src0 = (const float*)d_in[2];
  const float* a_dst0 = (const float*)d_in[3];
  const float* b0     = (const float*)d_in[4];
  const float* W1     = (const float*)d_in[5];
  const float* a_src1 = (const float*)d_in[6];
  const float* a_dst1 = (const float*)d_in[7];
  const float* b1     = (const float*)d_in[8];
  const int*   ei     = (const int*)d_in[9];
  const int E = in_sizes[9] / 2;
  const int Etot = E + N_NODES;
  float* out = (float*)d_out;
  (void)n_in; (void)out_size; (void)ws_size;

  char* ws = (char*)d_ws;
  size_t off = 0;
  auto alloc = [&](size_t bytes) -> char* {
    char* p = ws + off;
    off += (bytes + 255) & ~(size_t)255;
    return p;
  };
  ushort* h0b  = (ushort*)alloc((size_t)N_NODES * 256 * 2);
  ushort* hEb  = (ushort*)alloc((size_t)N_NODES * 256 * 2);
  ushort* h1b  = (ushort*)alloc((size_t)N_NODES * 128 * 2);
  ushort* W0T  = (ushort*)alloc((size_t)256 * 128 * 2);
  ushort* W1T  = (ushort*)alloc((size_t)128 * 256 * 2);
  int* counts  = (int*)alloc((size_t)N_NODES * 4);      // zero-init below
  float* ss0   = (float*)alloc((size_t)N_NODES * 2 * 4);  // direct-stored
  float* sd0   = (float*)alloc((size_t)N_NODES * 2 * 4);
  float* ss1   = (float*)alloc((size_t)N_NODES * 4);
  float* sd1   = (float*)alloc((size_t)N_NODES * 4);
  int* rowptr  = (int*)alloc((size_t)(N_NODES + 1) * 4);
  int* partial = (int*)alloc((size_t)N_NODES * 4);
  int* bsums   = (int*)alloc((size_t)64 * 4);
  ushort* rank = (ushort*)alloc((size_t)Etot * 2);
  unsigned* csrSD = (unsigned*)alloc((size_t)Etot * 4);

  hipMemsetAsync(counts, 0, (size_t)N_NODES * 4, stream);

  // ---- prep: weight transposes (one kernel) ----
  convT2_kernel<<<65536 / 256, 256, 0, stream>>>(W0, W0T, W1, W1T);

  // ---- CSR build, phase 1: hist + scans (scatter fused below) ----
  const int nblk = (N_NODES + 1023) / 1024;  // 49
  hist_kernel<<<(Etot + 255) / 256, 256, 0, stream>>>(ei, E, Etot, counts, rank);
  scan1_kernel<<<nblk, 1024, 0, stream>>>(counts, partial, bsums, N_NODES);
  scan23_kernel<<<(N_NODES + 255) / 256, 256, 0, stream>>>(partial, bsums, rowptr,
                                                           N_NODES, nblk);

  // ---- FUSED: layer-0 gemm (1564 blocks) + scatter (nS blocks) ----
  const int nS = (Etot + 255) / 256;
  const int grid = 3 * NG0 + ((nS > 2 * NG0) ? (nS - 2 * NG0) : 0);
  gemm0_scatter_kernel<<<grid, 256, 0, stream>>>(
      x, W0T, h0b, N_NODES, a_src0, a_dst0, ss0, sd0,
      ei, E, Etot, nS, rowptr, rank, csrSD);

  agg0_kernel<<<N_NODES / 4, 256, 0, stream>>>(h0b, ss0, sd0, rowptr, csrSD, b0, hEb);

  // ---- layer 1 ----
  dim3 g1(1, (N_NODES + 63) / 64);
  gemm_mfma<1, false><<<g1, 256, 0, stream>>>(hEb, W1T, h1b, N_NODES, 128, 256,
                                              a_src1, a_dst1, ss1, sd1);
  agg1_kernel<<<N_NODES / 4, 256, 0, stream>>>(h1b, ss1, sd1, rowptr, csrSD, b1,
                                               (const float2*)x, (float2*)out);
}

// Round 8
// 250.629 us; speedup vs baseline: 1.1324x; 1.0853x over previous
//
#include <hip/hip_runtime.h>

#define N_NODES 50000
#define NEG_SLOPE 0.2f

typedef short s8v __attribute__((ext_vector_type(8)));
typedef float f4v __attribute__((ext_vector_type(4)));

// ---- bf16 helpers (RNE) ---------------------------------------------------
__device__ __forceinline__ ushort f2bf(float f) {
  union { float f; unsigned u; } v; v.f = f;
  return (ushort)((v.u + 0x7FFFu + ((v.u >> 16) & 1u)) >> 16);
}
__device__ __forceinline__ float bf2f(ushort h) {
  union { unsigned u; float f; } v; v.u = ((unsigned)h) << 16;
  return v.f;
}

// ---- fp8 e4m3 helpers (HW cvt, gfx950 OCP e4m3fn) -------------------------
__device__ __forceinline__ unsigned char f2fp8(float f) {
  return (unsigned char)(__builtin_amdgcn_cvt_pk_fp8_f32(f, f, 0, false) & 0xFF);
}

// ---- MFMA GEMM, 64M x 128N tile + direct-store attention scores -----------
// R8/R10-proven structure — DO NOT restructure (R9's rewrite was flaky).
// (used for layer 1 only; bf16 C output)
template <int HEADS, bool AF32>
__global__ __launch_bounds__(256) void gemm_mfma(
    const void* __restrict__ Av, const ushort* __restrict__ BT,
    ushort* __restrict__ C, int M, int N, int K,
    const float* __restrict__ a_src, const float* __restrict__ a_dst,
    float* __restrict__ ss, float* __restrict__ sd) {
  __shared__ ushort As[64][136];   // +8 pad: 16B-aligned, 2-way banks (free)
  __shared__ ushort Bs[128][136];
  const int tid = threadIdx.x;
  const int w = tid >> 6, lane = tid & 63;
  const int q = lane >> 4, r16 = lane & 15;
  const int n0 = blockIdx.x * 128, m0 = blockIdx.y * 64;
  f4v acc[8] = {};
  for (int kc = 0; kc < K; kc += 128) {
#pragma unroll
    for (int i = 0; i < 4; ++i) {
      int c = tid + 256 * i;
      int row = c >> 4, ko = (c & 15) * 8;
      int gm = m0 + row;
      s8v va = {};
      if (gm < M) {
        if (AF32) {
          const float* A = (const float*)Av;
          float4 f0 = *reinterpret_cast<const float4*>(&A[(size_t)gm * K + kc + ko]);
          float4 f1 = *reinterpret_cast<const float4*>(&A[(size_t)gm * K + kc + ko + 4]);
          va[0] = (short)f2bf(f0.x); va[1] = (short)f2bf(f0.y);
          va[2] = (short)f2bf(f0.z); va[3] = (short)f2bf(f0.w);
          va[4] = (short)f2bf(f1.x); va[5] = (short)f2bf(f1.y);
          va[6] = (short)f2bf(f1.z); va[7] = (short)f2bf(f1.w);
        } else {
          const ushort* A = (const ushort*)Av;
          va = *reinterpret_cast<const s8v*>(&A[(size_t)gm * K + kc + ko]);
        }
      }
      *reinterpret_cast<s8v*>(&As[row][ko]) = va;
    }
#pragma unroll
    for (int i = 0; i < 8; ++i) {
      int c = tid + 256 * i;
      int row = c >> 4, ko = (c & 15) * 8;
      s8v vb = *reinterpret_cast<const s8v*>(&BT[(size_t)(n0 + row) * K + kc + ko]);
      *reinterpret_cast<s8v*>(&Bs[row][ko]) = vb;
    }
    __syncthreads();
#pragma unroll
    for (int ks = 0; ks < 4; ++ks) {
      s8v af = *reinterpret_cast<const s8v*>(&As[w * 16 + r16][ks * 32 + q * 8]);
#pragma unroll
      for (int nt = 0; nt < 8; ++nt) {
        s8v bf = *reinterpret_cast<const s8v*>(&Bs[nt * 16 + r16][ks * 32 + q * 8]);
        acc[nt] = __builtin_amdgcn_mfma_f32_16x16x32_bf16(af, bf, acc[nt], 0, 0, 0);
      }
    }
    __syncthreads();
  }
#pragma unroll
  for (int nt = 0; nt < 8; ++nt)
#pragma unroll
    for (int r = 0; r < 4; ++r) {
      int gm = m0 + w * 16 + q * 4 + r;
      if (gm < M) C[(size_t)gm * N + n0 + nt * 16 + r16] = f2bf(acc[nt][r]);
    }
  const int head = n0 >> 7;
  float ps[4] = {0.f, 0.f, 0.f, 0.f}, pd[4] = {0.f, 0.f, 0.f, 0.f};
#pragma unroll
  for (int nt = 0; nt < 8; ++nt) {
    int n = n0 + nt * 16 + r16;
    float as = a_src[n], ad = a_dst[n];
#pragma unroll
    for (int r = 0; r < 4; ++r) {
      ps[r] = fmaf(acc[nt][r], as, ps[r]);
      pd[r] = fmaf(acc[nt][r], ad, pd[r]);
    }
  }
#pragma unroll
  for (int off = 1; off < 16; off <<= 1) {
#pragma unroll
    for (int r = 0; r < 4; ++r) {
      ps[r] += __shfl_xor(ps[r], off);
      pd[r] += __shfl_xor(pd[r], off);
    }
  }
  if (r16 == 0) {
#pragma unroll
    for (int r = 0; r < 4; ++r) {
      int gm = m0 + w * 16 + q * 4 + r;
      if (gm < M) {
        ss[gm * HEADS + head] = ps[r];
        sd[gm * HEADS + head] = pd[r];
      }
    }
  }
}

// ---- FUSED: layer-0 GEMM + CSR scatter in one dispatch --------------------
// R15: C output is fp8-e4m3 (halves h0b bytes; agg0 is at the 8x-XCD
// compulsory L2-fill floor — FETCH 203 MB = 8 x 25.6 MB — so byte
// reduction is the only remaining lever there).
#define NG0 1564  // 2 * ceil(N_NODES/64)
__global__ __launch_bounds__(256) void gemm0_scatter_kernel(
    const float* __restrict__ A, const ushort* __restrict__ BT,
    unsigned char* __restrict__ C, int M,
    const float* __restrict__ a_src, const float* __restrict__ a_dst,
    float* __restrict__ ss, float* __restrict__ sd,
    const int* __restrict__ ei, int E, int Etot, int nS,
    const int* __restrict__ rowptr, const ushort* __restrict__ rank,
    unsigned* __restrict__ csrSD) {
  __shared__ ushort As[64][136];
  __shared__ ushort Bs[128][136];
  const int id = blockIdx.x;
  int gemmIdx = -1, sIdx = -1;
  if (id < 3 * NG0) {
    const int g = id / 3, r = id % 3;
    if (r == 0) gemmIdx = g;
    else        sIdx = 2 * g + (r - 1);
  } else {
    sIdx = 2 * NG0 + (id - 3 * NG0);
  }

  if (gemmIdx >= 0) {
    // ---- gemm body (HEADS=2, AF32, N=256, K=128), x-major block order ----
    const int nb = gemmIdx & 1, mb = gemmIdx >> 1;
    const int tid = threadIdx.x;
    const int w = tid >> 6, lane = tid & 63;
    const int q = lane >> 4, r16 = lane & 15;
    const int n0 = nb * 128, m0 = mb * 64;
    const int N = 256, K = 128;
    f4v acc[8] = {};
    for (int kc = 0; kc < K; kc += 128) {
#pragma unroll
      for (int i = 0; i < 4; ++i) {
        int c = tid + 256 * i;
        int row = c >> 4, ko = (c & 15) * 8;
        int gm = m0 + row;
        s8v va = {};
        if (gm < M) {
          float4 f0 = *reinterpret_cast<const float4*>(&A[(size_t)gm * K + kc + ko]);
          float4 f1 = *reinterpret_cast<const float4*>(&A[(size_t)gm * K + kc + ko + 4]);
          va[0] = (short)f2bf(f0.x); va[1] = (short)f2bf(f0.y);
          va[2] = (short)f2bf(f0.z); va[3] = (short)f2bf(f0.w);
          va[4] = (short)f2bf(f1.x); va[5] = (short)f2bf(f1.y);
          va[6] = (short)f2bf(f1.z); va[7] = (short)f2bf(f1.w);
        }
        *reinterpret_cast<s8v*>(&As[row][ko]) = va;
      }
#pragma unroll
      for (int i = 0; i < 8; ++i) {
        int c = tid + 256 * i;
        int row = c >> 4, ko = (c & 15) * 8;
        s8v vb = *reinterpret_cast<const s8v*>(&BT[(size_t)(n0 + row) * K + kc + ko]);
        *reinterpret_cast<s8v*>(&Bs[row][ko]) = vb;
      }
      __syncthreads();
#pragma unroll
      for (int ks = 0; ks < 4; ++ks) {
        s8v af = *reinterpret_cast<const s8v*>(&As[w * 16 + r16][ks * 32 + q * 8]);
#pragma unroll
        for (int nt = 0; nt < 8; ++nt) {
          s8v bf = *reinterpret_cast<const s8v*>(&Bs[nt * 16 + r16][ks * 32 + q * 8]);
          acc[nt] = __builtin_amdgcn_mfma_f32_16x16x32_bf16(af, bf, acc[nt], 0, 0, 0);
        }
      }
      __syncthreads();
    }
#pragma unroll
    for (int nt = 0; nt < 8; ++nt)
#pragma unroll
      for (int r = 0; r < 4; ++r) {
        int gm = m0 + w * 16 + q * 4 + r;
        if (gm < M) C[(size_t)gm * N + n0 + nt * 16 + r16] = f2fp8(acc[nt][r]);
      }
    const int head = n0 >> 7;
    float ps[4] = {0.f, 0.f, 0.f, 0.f}, pd[4] = {0.f, 0.f, 0.f, 0.f};
#pragma unroll
    for (int nt = 0; nt < 8; ++nt) {
      int n = n0 + nt * 16 + r16;
      float as = a_src[n], ad = a_dst[n];
#pragma unroll
      for (int r = 0; r < 4; ++r) {
        ps[r] = fmaf(acc[nt][r], as, ps[r]);
        pd[r] = fmaf(acc[nt][r], ad, pd[r]);
      }
    }
#pragma unroll
    for (int off = 1; off < 16; off <<= 1) {
#pragma unroll
      for (int r = 0; r < 4; ++r) {
        ps[r] += __shfl_xor(ps[r], off);
        pd[r] += __shfl_xor(pd[r], off);
      }
    }
    if (r16 == 0) {
#pragma unroll
      for (int r = 0; r < 4; ++r) {
        int gm = m0 + w * 16 + q * 4 + r;
        if (gm < M) {
          ss[gm * 2 + head] = ps[r];
          sd[gm * 2 + head] = pd[r];
        }
      }
    }
  } else {
    // ---- scatter body (verbatim from R12's scatter_kernel) ----
    if (sIdx >= nS) return;
    int e = sIdx * 256 + threadIdx.x;
    if (e >= Etot) return;
    int s, d;
    if (e < E) { s = ei[e]; d = ei[E + e]; } else { s = d = e - E; }
    csrSD[rowptr[d] + (int)rank[e]] = (unsigned)s | ((unsigned)d << 16);
  }
}

// ------------- CSR build: hist(+u16 rank, + fused weight transposes) -------
// R15: convT2 folded in (blocks 0..255 also transpose W0/W1) — one fewer
// dispatch; work is independent (different arrays).
__global__ void hist_kernel(const int* __restrict__ ei, int E, int Etot,
                            int* __restrict__ counts, ushort* __restrict__ rank,
                            const float* __restrict__ W0, ushort* __restrict__ W0T,
                            const float* __restrict__ W1, ushort* __restrict__ W1T) {
  int i = blockIdx.x * blockDim.x + threadIdx.x;
  if (i < 65536) {
    if (i < 32768) {
      int r = i >> 8, c = i & 255;           // W0: R=128, C=256
      W0T[c * 128 + r] = f2bf(W0[i]);
    } else {
      int j = i - 32768;
      int r = j >> 7, c = j & 127;           // W1: R=256, C=128
      W1T[c * 256 + r] = f2bf(W1[j]);
    }
  }
  int e = i;
  if (e >= Etot) return;
  int d = (e < E) ? ei[E + e] : (e - E);
  rank[e] = (ushort)atomicAdd(&counts[d], 1);  // degree << 65536
}

__global__ __launch_bounds__(1024) void scan1_kernel(const int* __restrict__ counts,
                                                     int* __restrict__ partial,
                                                     int* __restrict__ blocksums, int n) {
  __shared__ int tmp[1024];
  int i = blockIdx.x * 1024 + threadIdx.x;
  int v = (i < n) ? counts[i] : 0;
  tmp[threadIdx.x] = v;
  __syncthreads();
  for (int off = 1; off < 1024; off <<= 1) {
    int t = (threadIdx.x >= off) ? tmp[threadIdx.x - off] : 0;
    __syncthreads();
    tmp[threadIdx.x] += t;
    __syncthreads();
  }
  if (i < n) partial[i] = tmp[threadIdx.x];
  if (threadIdx.x == 1023) blocksums[blockIdx.x] = tmp[1023];
}

__global__ void scan23_kernel(const int* __restrict__ partial,
                              const int* __restrict__ blocksums,
                              int* __restrict__ rowptr, int n, int nb) {
  __shared__ int sb[64];
  int t = threadIdx.x;
  if (t < 64) {
    int v = (t < nb) ? blocksums[t] : 0;
#pragma unroll
    for (int off = 1; off < 64; off <<= 1) {
      int u = __shfl_up(v, off);
      if ((t & 63) >= off) v += u;
    }
    sb[t] = v;
  }
  __syncthreads();
  int i = blockIdx.x * blockDim.x + t;
  if (i == 0) rowptr[0] = 0;
  if (i < n) {
    int b = i >> 10;
    int add = (b > 0) ? sb[b - 1] : 0;
    rowptr[i + 1] = partial[i] + add;
  }
}

// ---- layer-0 aggregation: fp8 h0 gather (R15) -----------------------------
// agg0 was at the compulsory L2-fill floor (FETCH = 8 XCD x h0 bytes) at a
// fixed ~3.9 TB/s fill rate (MSHR x latency ceiling; 4/8-deep + scalarized
// variants all null). fp8 rows halve lines/row -> 2x row rate at the same
// line-rate ceiling. Scores ss/sd stay exact f32.
__global__ __launch_bounds__(256) void agg0_kernel(
    const unsigned char* __restrict__ h0,   // [N,256] fp8 e4m3
    const float* __restrict__ ss, const float* __restrict__ sd,  // [N,2]
    const int* __restrict__ rowptr, const unsigned* __restrict__ csrSD,
    const float* __restrict__ b0, ushort* __restrict__ hE) {
  const int n = __builtin_amdgcn_readfirstlane(blockIdx.x * 4 + (threadIdx.x >> 6));
  const int t = threadIdx.x & 63;
  const int hd = t >> 5;
  const float2 sdv = *reinterpret_cast<const float2*>(&sd[n * 2]);
  const float sdn = hd ? sdv.y : sdv.x;
  float a0 = 0.f, a1 = 0.f, a2 = 0.f, a3 = 0.f, den = 0.f;
  int p = __builtin_amdgcn_readfirstlane(rowptr[n]);
  const int p1 = __builtin_amdgcn_readfirstlane(rowptr[n + 1]);
  for (; p + 8 <= p1; p += 8) {  // 8 rows in flight per wave
    int s[8];
#pragma unroll
    for (int j = 0; j < 8; ++j)
      s[j] = __builtin_amdgcn_readfirstlane((int)(csrSD[p + j] & 0xFFFFu));
    unsigned v[8];
#pragma unroll
    for (int j = 0; j < 8; ++j) {
      const unsigned char* row = h0 + (size_t)s[j] * 256;   // SGPR base
      v[j] = *reinterpret_cast<const unsigned*>(row + t * 4);
    }
    float w[8];
#pragma unroll
    for (int j = 0; j < 8; ++j) {
      const float2 sv = *reinterpret_cast<const float2*>(&ss[s[j] * 2]);
      float e = (hd ? sv.y : sv.x) + sdn;
      e = (e > 0.f) ? e : NEG_SLOPE * e;
      w[j] = __expf(e);
    }
#pragma unroll
    for (int j = 0; j < 8; ++j) {
      den += w[j];
      a0 = fmaf(w[j], __builtin_amdgcn_cvt_f32_fp8(v[j], 0), a0);
      a1 = fmaf(w[j], __builtin_amdgcn_cvt_f32_fp8(v[j], 1), a1);
      a2 = fmaf(w[j], __builtin_amdgcn_cvt_f32_fp8(v[j], 2), a2);
      a3 = fmaf(w[j], __builtin_amdgcn_cvt_f32_fp8(v[j], 3), a3);
    }
  }
  for (; p + 4 <= p1; p += 4) {
    int s[4];
#pragma unroll
    for (int j = 0; j < 4; ++j)
      s[j] = __builtin_amdgcn_readfirstlane((int)(csrSD[p + j] & 0xFFFFu));
    unsigned v[4];
#pragma unroll
    for (int j = 0; j < 4; ++j) {
      const unsigned char* row = h0 + (size_t)s[j] * 256;
      v[j] = *reinterpret_cast<const unsigned*>(row + t * 4);
    }
    float w[4];
#pragma unroll
    for (int j = 0; j < 4; ++j) {
      const float2 sv = *reinterpret_cast<const float2*>(&ss[s[j] * 2]);
      float e = (hd ? sv.y : sv.x) + sdn;
      e = (e > 0.f) ? e : NEG_SLOPE * e;
      w[j] = __expf(e);
    }
#pragma unroll
    for (int j = 0; j < 4; ++j) {
      den += w[j];
      a0 = fmaf(w[j], __builtin_amdgcn_cvt_f32_fp8(v[j], 0), a0);
      a1 = fmaf(w[j], __builtin_amdgcn_cvt_f32_fp8(v[j], 1), a1);
      a2 = fmaf(w[j], __builtin_amdgcn_cvt_f32_fp8(v[j], 2), a2);
      a3 = fmaf(w[j], __builtin_amdgcn_cvt_f32_fp8(v[j], 3), a3);
    }
  }
  for (; p < p1; ++p) {
    const int sj = __builtin_amdgcn_readfirstlane((int)(csrSD[p] & 0xFFFFu));
    const float2 sv = *reinterpret_cast<const float2*>(&ss[sj * 2]);
    float e = (hd ? sv.y : sv.x) + sdn;
    e = (e > 0.f) ? e : NEG_SLOPE * e;
    const float wj = __expf(e);
    const unsigned char* row = h0 + (size_t)sj * 256;
    const unsigned vj = *reinterpret_cast<const unsigned*>(row + t * 4);
    den += wj;
    a0 = fmaf(wj, __builtin_amdgcn_cvt_f32_fp8(vj, 0), a0);
    a1 = fmaf(wj, __builtin_amdgcn_cvt_f32_fp8(vj, 1), a1);
    a2 = fmaf(wj, __builtin_amdgcn_cvt_f32_fp8(vj, 2), a2);
    a3 = fmaf(wj, __builtin_amdgcn_cvt_f32_fp8(vj, 3), a3);
  }
  const float inv = 1.f / den;
  const float4 bv = reinterpret_cast<const float4*>(b0)[t];
  float o[4] = {fmaf(a0, inv, bv.x), fmaf(a1, inv, bv.y),
                fmaf(a2, inv, bv.z), fmaf(a3, inv, bv.w)};
#pragma unroll
  for (int i = 0; i < 4; ++i) o[i] = (o[i] > 0.f) ? o[i] : (__expf(o[i]) - 1.f);
  ushort4 ov; ov.x = f2bf(o[0]); ov.y = f2bf(o[1]); ov.z = f2bf(o[2]); ov.w = f2bf(o[3]);
  *reinterpret_cast<ushort4*>(&hE[(size_t)n * 256 + t * 4]) = ov;
}

// ---- layer-1 aggregation: SGPR-scalarized (unchanged; bf16 h1) ------------
__global__ __launch_bounds__(256) void agg1_kernel(
    const ushort* __restrict__ h1,   // [N,128] bf16
    const float* __restrict__ ss, const float* __restrict__ sd,  // [N]
    const int* __restrict__ rowptr, const unsigned* __restrict__ csrSD,
    const float* __restrict__ b1, const float2* __restrict__ x,
    float2* __restrict__ out) {
  const int n = __builtin_amdgcn_readfirstlane(blockIdx.x * 4 + (threadIdx.x >> 6));
  const int t = threadIdx.x & 63;
  const float sdn = sd[n];
  float a0 = 0.f, a1 = 0.f, den = 0.f;
  int p = __builtin_amdgcn_readfirstlane(rowptr[n]);
  const int p1 = __builtin_amdgcn_readfirstlane(rowptr[n + 1]);
  for (; p + 8 <= p1; p += 8) {
    int s[8];
#pragma unroll
    for (int j = 0; j < 8; ++j)
      s[j] = __builtin_amdgcn_readfirstlane((int)(csrSD[p + j] & 0xFFFFu));
    ushort2 v[8];
#pragma unroll
    for (int j = 0; j < 8; ++j) {
      const ushort* row = h1 + (size_t)s[j] * 128;
      v[j] = *reinterpret_cast<const ushort2*>(row + t * 2);
    }
    float w[8];
#pragma unroll
    for (int j = 0; j < 8; ++j) {
      float e = ss[s[j]] + sdn;
      e = (e > 0.f) ? e : NEG_SLOPE * e;
      w[j] = __expf(e);
    }
#pragma unroll
    for (int j = 0; j < 8; ++j) {
      den += w[j];
      a0 = fmaf(w[j], bf2f(v[j].x), a0);
      a1 = fmaf(w[j], bf2f(v[j].y), a1);
    }
  }
  for (; p + 4 <= p1; p += 4) {
    int s[4];
#pragma unroll
    for (int j = 0; j < 4; ++j)
      s[j] = __builtin_amdgcn_readfirstlane((int)(csrSD[p + j] & 0xFFFFu));
    ushort2 v[4];
#pragma unroll
    for (int j = 0; j < 4; ++j) {
      const ushort* row = h1 + (size_t)s[j] * 128;
      v[j] = *reinterpret_cast<const ushort2*>(row + t * 2);
    }
    float w[4];
#pragma unroll
    for (int j = 0; j < 4; ++j) {
      float e = ss[s[j]] + sdn;
      e = (e > 0.f) ? e : NEG_SLOPE * e;
      w[j] = __expf(e);
    }
#pragma unroll
    for (int j = 0; j < 4; ++j) {
      den += w[j];
      a0 = fmaf(w[j], bf2f(v[j].x), a0);
      a1 = fmaf(w[j], bf2f(v[j].y), a1);
    }
  }
  for (; p < p1; ++p) {
    const int sj = __builtin_amdgcn_readfirstlane((int)(csrSD[p] & 0xFFFFu));
    float e = ss[sj] + sdn;
    e = (e > 0.f) ? e : NEG_SLOPE * e;
    const float wj = __expf(e);
    const ushort* row = h1 + (size_t)sj * 128;
    const ushort2 vj = *reinterpret_cast<const ushort2*>(row + t * 2);
    den += wj;
    a0 = fmaf(wj, bf2f(vj.x), a0);
    a1 = fmaf(wj, bf2f(vj.y), a1);
  }
  const float inv = 1.f / den;
  const float2 bv = reinterpret_cast<const float2*>(b1)[t];
  const float2 xv = x[(size_t)n * 64 + t];
  out[(size_t)n * 64 + t] =
      make_float2(xv.x + fmaf(a0, inv, bv.x), xv.y + fmaf(a1, inv, bv.y));
}

extern "C" void kernel_launch(void* const* d_in, const int* in_sizes, int n_in,
                              void* d_out, int out_size, void* d_ws, size_t ws_size,
                              hipStream_t stream) {
  const float* x      = (const float*)d_in[0];
  const float* W0     = (const float*)d_in[1];
  const float* a_src0 = (const float*)d_in[2];
  const float* a_dst0 = (const float*)d_in[3];
  const float* b0     = (const float*)d_in[4];
  const float* W1     = (const float*)d_in[5];
  const float* a_src1 = (const float*)d_in[6];
  const float* a_dst1 = (const float*)d_in[7];
  const float* b1     = (const float*)d_in[8];
  const int*   ei     = (const int*)d_in[9];
  const int E = in_sizes[9] / 2;
  const int Etot = E + N_NODES;
  float* out = (float*)d_out;
  (void)n_in; (void)out_size; (void)ws_size;

  char* ws = (char*)d_ws;
  size_t off = 0;
  auto alloc = [&](size_t bytes) -> char* {
    char* p = ws + off;
    off += (bytes + 255) & ~(size_t)255;
    return p;
  };
  unsigned char* h0b = (unsigned char*)alloc((size_t)N_NODES * 256);  // fp8
  ushort* hEb  = (ushort*)alloc((size_t)N_NODES * 256 * 2);
  ushort* h1b  = (ushort*)alloc((size_t)N_NODES * 128 * 2);
  ushort* W0T  = (ushort*)alloc((size_t)256 * 128 * 2);
  ushort* W1T  = (ushort*)alloc((size_t)128 * 256 * 2);
  int* counts  = (int*)alloc((size_t)N_NODES * 4);      // zero-init below
  float* ss0   = (float*)alloc((size_t)N_NODES * 2 * 4);  // direct-stored
  float* sd0   = (float*)alloc((size_t)N_NODES * 2 * 4);
  float* ss1   = (float*)alloc((size_t)N_NODES * 4);
  float* sd1   = (float*)alloc((size_t)N_NODES * 4);
  int* rowptr  = (int*)alloc((size_t)(N_NODES + 1) * 4);
  int* partial = (int*)alloc((size_t)N_NODES * 4);
  int* bsums   = (int*)alloc((size_t)64 * 4);
  ushort* rank = (ushort*)alloc((size_t)Etot * 2);
  unsigned* csrSD = (unsigned*)alloc((size_t)Etot * 4);

  hipMemsetAsync(counts, 0, (size_t)N_NODES * 4, stream);

  // ---- CSR build phase 1 (+ fused weight transposes) ----
  const int nblk = (N_NODES + 1023) / 1024;  // 49
  hist_kernel<<<(Etot + 255) / 256, 256, 0, stream>>>(ei, E, Etot, counts, rank,
                                                      W0, W0T, W1, W1T);
  scan1_kernel<<<nblk, 1024, 0, stream>>>(counts, partial, bsums, N_NODES);
  scan23_kernel<<<(N_NODES + 255) / 256, 256, 0, stream>>>(partial, bsums, rowptr,
                                                           N_NODES, nblk);

  // ---- FUSED: layer-0 gemm (1564 blocks) + scatter (nS blocks) ----
  const int nS = (Etot + 255) / 256;
  const int grid = 3 * NG0 + ((nS > 2 * NG0) ? (nS - 2 * NG0) : 0);
  gemm0_scatter_kernel<<<grid, 256, 0, stream>>>(
      x, W0T, h0b, N_NODES, a_src0, a_dst0, ss0, sd0,
      ei, E, Etot, nS, rowptr, rank, csrSD);

  agg0_kernel<<<N_NODES / 4, 256, 0, stream>>>(h0b, ss0, sd0, rowptr, csrSD, b0, hEb);

  // ---- layer 1 ----
  dim3 g1(1, (N_NODES + 63) / 64);
  gemm_mfma<1, false><<<g1, 256, 0, stream>>>(hEb, W1T, h1b, N_NODES, 128, 256,
                                              a_src1, a_dst1, ss1, sd1);
  agg1_kernel<<<N_NODES / 4, 256, 0, stream>>>(h1b, ss1, sd1, rowptr, csrSD, b1,
                                               (const float2*)x, (float2*)out);
}

// Round 16
// 248.006 us; speedup vs baseline: 1.1444x; 1.0106x over previous
//
#include <hip/hip_runtime.h>

#define N_NODES 50000
#define NEG_SLOPE 0.2f

typedef short s8v __attribute__((ext_vector_type(8)));
typedef float f4v __attribute__((ext_vector_type(4)));

// ---- bf16 helpers (RNE) ---------------------------------------------------
__device__ __forceinline__ ushort f2bf(float f) {
  union { float f; unsigned u; } v; v.f = f;
  return (ushort)((v.u + 0x7FFFu + ((v.u >> 16) & 1u)) >> 16);
}
__device__ __forceinline__ float bf2f(ushort h) {
  union { unsigned u; float f; } v; v.u = ((unsigned)h) << 16;
  return v.f;
}

// ---- fp8 e4m3 helpers (HW cvt, gfx950 OCP e4m3fn) -------------------------
__device__ __forceinline__ unsigned char f2fp8(float f) {
  return (unsigned char)(__builtin_amdgcn_cvt_pk_fp8_f32(f, f, 0, false) & 0xFF);
}

// ---- MFMA GEMM, 64M x 128N tile + direct-store attention scores -----------
// R8/R10-proven structure — DO NOT restructure (R9's rewrite was flaky).
// R17: fp8-h1 REVERTED (R16 failed: absmax 0.156 > 0.114. Layer-1 value
// path has NO downstream contraction — fp8 noise lands on out unattenuated,
// ~2x the modeled tail. fp8 stays on h0 only, where W1 contraction
// attenuates it.)
template <int HEADS, bool AF32>
__global__ __launch_bounds__(256) void gemm_mfma(
    const void* __restrict__ Av, const ushort* __restrict__ BT,
    ushort* __restrict__ C, int M, int N, int K,
    const float* __restrict__ a_src, const float* __restrict__ a_dst,
    float* __restrict__ ss, float* __restrict__ sd) {
  __shared__ ushort As[64][136];   // +8 pad: 16B-aligned, 2-way banks (free)
  __shared__ ushort Bs[128][136];
  const int tid = threadIdx.x;
  const int w = tid >> 6, lane = tid & 63;
  const int q = lane >> 4, r16 = lane & 15;
  const int n0 = blockIdx.x * 128, m0 = blockIdx.y * 64;
  f4v acc[8] = {};
  for (int kc = 0; kc < K; kc += 128) {
#pragma unroll
    for (int i = 0; i < 4; ++i) {
      int c = tid + 256 * i;
      int row = c >> 4, ko = (c & 15) * 8;
      int gm = m0 + row;
      s8v va = {};
      if (gm < M) {
        if (AF32) {
          const float* A = (const float*)Av;
          float4 f0 = *reinterpret_cast<const float4*>(&A[(size_t)gm * K + kc + ko]);
          float4 f1 = *reinterpret_cast<const float4*>(&A[(size_t)gm * K + kc + ko + 4]);
          va[0] = (short)f2bf(f0.x); va[1] = (short)f2bf(f0.y);
          va[2] = (short)f2bf(f0.z); va[3] = (short)f2bf(f0.w);
          va[4] = (short)f2bf(f1.x); va[5] = (short)f2bf(f1.y);
          va[6] = (short)f2bf(f1.z); va[7] = (short)f2bf(f1.w);
        } else {
          const ushort* A = (const ushort*)Av;
          va = *reinterpret_cast<const s8v*>(&A[(size_t)gm * K + kc + ko]);
        }
      }
      *reinterpret_cast<s8v*>(&As[row][ko]) = va;
    }
#pragma unroll
    for (int i = 0; i < 8; ++i) {
      int c = tid + 256 * i;
      int row = c >> 4, ko = (c & 15) * 8;
      s8v vb = *reinterpret_cast<const s8v*>(&BT[(size_t)(n0 + row) * K + kc + ko]);
      *reinterpret_cast<s8v*>(&Bs[row][ko]) = vb;
    }
    __syncthreads();
#pragma unroll
    for (int ks = 0; ks < 4; ++ks) {
      s8v af = *reinterpret_cast<const s8v*>(&As[w * 16 + r16][ks * 32 + q * 8]);
#pragma unroll
      for (int nt = 0; nt < 8; ++nt) {
        s8v bf = *reinterpret_cast<const s8v*>(&Bs[nt * 16 + r16][ks * 32 + q * 8]);
        acc[nt] = __builtin_amdgcn_mfma_f32_16x16x32_bf16(af, bf, acc[nt], 0, 0, 0);
      }
    }
    __syncthreads();
  }
#pragma unroll
  for (int nt = 0; nt < 8; ++nt)
#pragma unroll
    for (int r = 0; r < 4; ++r) {
      int gm = m0 + w * 16 + q * 4 + r;
      if (gm < M) C[(size_t)gm * N + n0 + nt * 16 + r16] = f2bf(acc[nt][r]);
    }
  const int head = n0 >> 7;
  float ps[4] = {0.f, 0.f, 0.f, 0.f}, pd[4] = {0.f, 0.f, 0.f, 0.f};
#pragma unroll
  for (int nt = 0; nt < 8; ++nt) {
    int n = n0 + nt * 16 + r16;
    float as = a_src[n], ad = a_dst[n];
#pragma unroll
    for (int r = 0; r < 4; ++r) {
      ps[r] = fmaf(acc[nt][r], as, ps[r]);
      pd[r] = fmaf(acc[nt][r], ad, pd[r]);
    }
  }
#pragma unroll
  for (int off = 1; off < 16; off <<= 1) {
#pragma unroll
    for (int r = 0; r < 4; ++r) {
      ps[r] += __shfl_xor(ps[r], off);
      pd[r] += __shfl_xor(pd[r], off);
    }
  }
  if (r16 == 0) {
#pragma unroll
    for (int r = 0; r < 4; ++r) {
      int gm = m0 + w * 16 + q * 4 + r;
      if (gm < M) {
        ss[gm * HEADS + head] = ps[r];
        sd[gm * HEADS + head] = pd[r];
      }
    }
  }
}

// ---- FUSED: layer-0 GEMM + CSR scatter in one dispatch --------------------
// R15: C output is fp8-e4m3 (halves h0b bytes; agg0 is at the 8x-XCD
// compulsory L2-fill floor — FETCH 203 MB = 8 x 25.6 MB — so byte
// reduction is the only remaining lever there). CONFIRMED R8: -21 us E2E,
// absmax 0.078 (fp8-h0 error is attenuated by the downstream W1 contraction).
#define NG0 1564  // 2 * ceil(N_NODES/64)
__global__ __launch_bounds__(256) void gemm0_scatter_kernel(
    const float* __restrict__ A, const ushort* __restrict__ BT,
    unsigned char* __restrict__ C, int M,
    const float* __restrict__ a_src, const float* __restrict__ a_dst,
    float* __restrict__ ss, float* __restrict__ sd,
    const int* __restrict__ ei, int E, int Etot, int nS,
    const int* __restrict__ rowptr, const ushort* __restrict__ rank,
    unsigned* __restrict__ csrSD) {
  __shared__ ushort As[64][136];
  __shared__ ushort Bs[128][136];
  const int id = blockIdx.x;
  int gemmIdx = -1, sIdx = -1;
  if (id < 3 * NG0) {
    const int g = id / 3, r = id % 3;
    if (r == 0) gemmIdx = g;
    else        sIdx = 2 * g + (r - 1);
  } else {
    sIdx = 2 * NG0 + (id - 3 * NG0);
  }

  if (gemmIdx >= 0) {
    // ---- gemm body (HEADS=2, AF32, N=256, K=128), x-major block order ----
    const int nb = gemmIdx & 1, mb = gemmIdx >> 1;
    const int tid = threadIdx.x;
    const int w = tid >> 6, lane = tid & 63;
    const int q = lane >> 4, r16 = lane & 15;
    const int n0 = nb * 128, m0 = mb * 64;
    const int N = 256, K = 128;
    f4v acc[8] = {};
    for (int kc = 0; kc < K; kc += 128) {
#pragma unroll
      for (int i = 0; i < 4; ++i) {
        int c = tid + 256 * i;
        int row = c >> 4, ko = (c & 15) * 8;
        int gm = m0 + row;
        s8v va = {};
        if (gm < M) {
          float4 f0 = *reinterpret_cast<const float4*>(&A[(size_t)gm * K + kc + ko]);
          float4 f1 = *reinterpret_cast<const float4*>(&A[(size_t)gm * K + kc + ko + 4]);
          va[0] = (short)f2bf(f0.x); va[1] = (short)f2bf(f0.y);
          va[2] = (short)f2bf(f0.z); va[3] = (short)f2bf(f0.w);
          va[4] = (short)f2bf(f1.x); va[5] = (short)f2bf(f1.y);
          va[6] = (short)f2bf(f1.z); va[7] = (short)f2bf(f1.w);
        }
        *reinterpret_cast<s8v*>(&As[row][ko]) = va;
      }
#pragma unroll
      for (int i = 0; i < 8; ++i) {
        int c = tid + 256 * i;
        int row = c >> 4, ko = (c & 15) * 8;
        s8v vb = *reinterpret_cast<const s8v*>(&BT[(size_t)(n0 + row) * K + kc + ko]);
        *reinterpret_cast<s8v*>(&Bs[row][ko]) = vb;
      }
      __syncthreads();
#pragma unroll
      for (int ks = 0; ks < 4; ++ks) {
        s8v af = *reinterpret_cast<const s8v*>(&As[w * 16 + r16][ks * 32 + q * 8]);
#pragma unroll
        for (int nt = 0; nt < 8; ++nt) {
          s8v bf = *reinterpret_cast<const s8v*>(&Bs[nt * 16 + r16][ks * 32 + q * 8]);
          acc[nt] = __builtin_amdgcn_mfma_f32_16x16x32_bf16(af, bf, acc[nt], 0, 0, 0);
        }
      }
      __syncthreads();
    }
#pragma unroll
    for (int nt = 0; nt < 8; ++nt)
#pragma unroll
      for (int r = 0; r < 4; ++r) {
        int gm = m0 + w * 16 + q * 4 + r;
        if (gm < M) C[(size_t)gm * N + n0 + nt * 16 + r16] = f2fp8(acc[nt][r]);
      }
    const int head = n0 >> 7;
    float ps[4] = {0.f, 0.f, 0.f, 0.f}, pd[4] = {0.f, 0.f, 0.f, 0.f};
#pragma unroll
    for (int nt = 0; nt < 8; ++nt) {
      int n = n0 + nt * 16 + r16;
      float as = a_src[n], ad = a_dst[n];
#pragma unroll
      for (int r = 0; r < 4; ++r) {
        ps[r] = fmaf(acc[nt][r], as, ps[r]);
        pd[r] = fmaf(acc[nt][r], ad, pd[r]);
      }
    }
#pragma unroll
    for (int off = 1; off < 16; off <<= 1) {
#pragma unroll
      for (int r = 0; r < 4; ++r) {
        ps[r] += __shfl_xor(ps[r], off);
        pd[r] += __shfl_xor(pd[r], off);
      }
    }
    if (r16 == 0) {
#pragma unroll
      for (int r = 0; r < 4; ++r) {
        int gm = m0 + w * 16 + q * 4 + r;
        if (gm < M) {
          ss[gm * 2 + head] = ps[r];
          sd[gm * 2 + head] = pd[r];
        }
      }
    }
  } else {
    // ---- scatter body (verbatim from R12's scatter_kernel) ----
    if (sIdx >= nS) return;
    int e = sIdx * 256 + threadIdx.x;
    if (e >= Etot) return;
    int s, d;
    if (e < E) { s = ei[e]; d = ei[E + e]; } else { s = d = e - E; }
    csrSD[rowptr[d] + (int)rank[e]] = (unsigned)s | ((unsigned)d << 16);
  }
}

// ------------- CSR build: hist(+u16 rank, + fused weight transposes) -------
__global__ void hist_kernel(const int* __restrict__ ei, int E, int Etot,
                            int* __restrict__ counts, ushort* __restrict__ rank,
                            const float* __restrict__ W0, ushort* __restrict__ W0T,
                            const float* __restrict__ W1, ushort* __restrict__ W1T) {
  int i = blockIdx.x * blockDim.x + threadIdx.x;
  if (i < 65536) {
    if (i < 32768) {
      int r = i >> 8, c = i & 255;           // W0: R=128, C=256
      W0T[c * 128 + r] = f2bf(W0[i]);
    } else {
      int j = i - 32768;
      int r = j >> 7, c = j & 127;           // W1: R=256, C=128
      W1T[c * 256 + r] = f2bf(W1[j]);
    }
  }
  int e = i;
  if (e >= Etot) return;
  int d = (e < E) ? ei[E + e] : (e - E);
  rank[e] = (ushort)atomicAdd(&counts[d], 1);  // degree << 65536
}

// R17: wave-shuffle scan (2 barriers instead of 20; exact integer math).
__global__ __launch_bounds__(1024) void scan1_kernel(const int* __restrict__ counts,
                                                     int* __restrict__ partial,
                                                     int* __restrict__ blocksums, int n) {
  __shared__ int wsum[16];
  const int i = blockIdx.x * 1024 + threadIdx.x;
  const int lane = threadIdx.x & 63, wid = threadIdx.x >> 6;
  int s = (i < n) ? counts[i] : 0;
#pragma unroll
  for (int off = 1; off < 64; off <<= 1) {
    int u = __shfl_up(s, off);
    if (lane >= off) s += u;
  }
  if (lane == 63) wsum[wid] = s;
  __syncthreads();
  if (wid == 0 && lane < 16) {
    int ws = wsum[lane];
#pragma unroll
    for (int off = 1; off < 16; off <<= 1) {
      int u = __shfl_up(ws, off);
      if (lane >= off) ws += u;
    }
    wsum[lane] = ws;
  }
  __syncthreads();
  if (wid > 0) s += wsum[wid - 1];
  if (i < n) partial[i] = s;
  if (threadIdx.x == 1023) blocksums[blockIdx.x] = s;
}

__global__ void scan23_kernel(const int* __restrict__ partial,
                              const int* __restrict__ blocksums,
                              int* __restrict__ rowptr, int n, int nb) {
  __shared__ int sb[64];
  int t = threadIdx.x;
  if (t < 64) {
    int v = (t < nb) ? blocksums[t] : 0;
#pragma unroll
    for (int off = 1; off < 64; off <<= 1) {
      int u = __shfl_up(v, off);
      if ((t & 63) >= off) v += u;
    }
    sb[t] = v;
  }
  __syncthreads();
  int i = blockIdx.x * blockDim.x + t;
  if (i == 0) rowptr[0] = 0;
  if (i < n) {
    int b = i >> 10;
    int add = (b > 0) ? sb[b - 1] : 0;
    rowptr[i + 1] = partial[i] + add;
  }
}

// ---- layer-0 aggregation: fp8 h0 gather (R15, confirmed R8) ---------------
__global__ __launch_bounds__(256) void agg0_kernel(
    const unsigned char* __restrict__ h0,   // [N,256] fp8 e4m3
    const float* __restrict__ ss, const float* __restrict__ sd,  // [N,2]
    const int* __restrict__ rowptr, const unsigned* __restrict__ csrSD,
    const float* __restrict__ b0, ushort* __restrict__ hE) {
  const int n = __builtin_amdgcn_readfirstlane(blockIdx.x * 4 + (threadIdx.x >> 6));
  const int t = threadIdx.x & 63;
  const int hd = t >> 5;
  const float2 sdv = *reinterpret_cast<const float2*>(&sd[n * 2]);
  const float sdn = hd ? sdv.y : sdv.x;
  float a0 = 0.f, a1 = 0.f, a2 = 0.f, a3 = 0.f, den = 0.f;
  int p = __builtin_amdgcn_readfirstlane(rowptr[n]);
  const int p1 = __builtin_amdgcn_readfirstlane(rowptr[n + 1]);
  for (; p + 8 <= p1; p += 8) {  // 8 rows in flight per wave
    int s[8];
#pragma unroll
    for (int j = 0; j < 8; ++j)
      s[j] = __builtin_amdgcn_readfirstlane((int)(csrSD[p + j] & 0xFFFFu));
    unsigned v[8];
#pragma unroll
    for (int j = 0; j < 8; ++j) {
      const unsigned char* row = h0 + (size_t)s[j] * 256;   // SGPR base
      v[j] = *reinterpret_cast<const unsigned*>(row + t * 4);
    }
    float w[8];
#pragma unroll
    for (int j = 0; j < 8; ++j) {
      const float2 sv = *reinterpret_cast<const float2*>(&ss[s[j] * 2]);
      float e = (hd ? sv.y : sv.x) + sdn;
      e = (e > 0.f) ? e : NEG_SLOPE * e;
      w[j] = __expf(e);
    }
#pragma unroll
    for (int j = 0; j < 8; ++j) {
      den += w[j];
      a0 = fmaf(w[j], __builtin_amdgcn_cvt_f32_fp8(v[j], 0), a0);
      a1 = fmaf(w[j], __builtin_amdgcn_cvt_f32_fp8(v[j], 1), a1);
      a2 = fmaf(w[j], __builtin_amdgcn_cvt_f32_fp8(v[j], 2), a2);
      a3 = fmaf(w[j], __builtin_amdgcn_cvt_f32_fp8(v[j], 3), a3);
    }
  }
  for (; p + 4 <= p1; p += 4) {
    int s[4];
#pragma unroll
    for (int j = 0; j < 4; ++j)
      s[j] = __builtin_amdgcn_readfirstlane((int)(csrSD[p + j] & 0xFFFFu));
    unsigned v[4];
#pragma unroll
    for (int j = 0; j < 4; ++j) {
      const unsigned char* row = h0 + (size_t)s[j] * 256;
      v[j] = *reinterpret_cast<const unsigned*>(row + t * 4);
    }
    float w[4];
#pragma unroll
    for (int j = 0; j < 4; ++j) {
      const float2 sv = *reinterpret_cast<const float2*>(&ss[s[j] * 2]);
      float e = (hd ? sv.y : sv.x) + sdn;
      e = (e > 0.f) ? e : NEG_SLOPE * e;
      w[j] = __expf(e);
    }
#pragma unroll
    for (int j = 0; j < 4; ++j) {
      den += w[j];
      a0 = fmaf(w[j], __builtin_amdgcn_cvt_f32_fp8(v[j], 0), a0);
      a1 = fmaf(w[j], __builtin_amdgcn_cvt_f32_fp8(v[j], 1), a1);
      a2 = fmaf(w[j], __builtin_amdgcn_cvt_f32_fp8(v[j], 2), a2);
      a3 = fmaf(w[j], __builtin_amdgcn_cvt_f32_fp8(v[j], 3), a3);
    }
  }
  for (; p < p1; ++p) {
    const int sj = __builtin_amdgcn_readfirstlane((int)(csrSD[p] & 0xFFFFu));
    const float2 sv = *reinterpret_cast<const float2*>(&ss[sj * 2]);
    float e = (hd ? sv.y : sv.x) + sdn;
    e = (e > 0.f) ? e : NEG_SLOPE * e;
    const float wj = __expf(e);
    const unsigned char* row = h0 + (size_t)sj * 256;
    const unsigned vj = *reinterpret_cast<const unsigned*>(row + t * 4);
    den += wj;
    a0 = fmaf(wj, __builtin_amdgcn_cvt_f32_fp8(vj, 0), a0);
    a1 = fmaf(wj, __builtin_amdgcn_cvt_f32_fp8(vj, 1), a1);
    a2 = fmaf(wj, __builtin_amdgcn_cvt_f32_fp8(vj, 2), a2);
    a3 = fmaf(wj, __builtin_amdgcn_cvt_f32_fp8(vj, 3), a3);
  }
  const float inv = 1.f / den;
  const float4 bv = reinterpret_cast<const float4*>(b0)[t];
  float o[4] = {fmaf(a0, inv, bv.x), fmaf(a1, inv, bv.y),
                fmaf(a2, inv, bv.z), fmaf(a3, inv, bv.w)};
#pragma unroll
  for (int i = 0; i < 4; ++i) o[i] = (o[i] > 0.f) ? o[i] : (__expf(o[i]) - 1.f);
  ushort4 ov; ov.x = f2bf(o[0]); ov.y = f2bf(o[1]); ov.z = f2bf(o[2]); ov.w = f2bf(o[3]);
  *reinterpret_cast<ushort4*>(&hE[(size_t)n * 256 + t * 4]) = ov;
}

// ---- layer-1 aggregation: bf16 h1 gather (R17: fp8 reverted) --------------
__global__ __launch_bounds__(256) void agg1_kernel(
    const ushort* __restrict__ h1,   // [N,128] bf16
    const float* __restrict__ ss, const float* __restrict__ sd,  // [N]
    const int* __restrict__ rowptr, const unsigned* __restrict__ csrSD,
    const float* __restrict__ b1, const float2* __restrict__ x,
    float2* __restrict__ out) {
  const int n = __builtin_amdgcn_readfirstlane(blockIdx.x * 4 + (threadIdx.x >> 6));
  const int t = threadIdx.x & 63;
  const float sdn = sd[n];
  float a0 = 0.f, a1 = 0.f, den = 0.f;
  int p = __builtin_amdgcn_readfirstlane(rowptr[n]);
  const int p1 = __builtin_amdgcn_readfirstlane(rowptr[n + 1]);
  for (; p + 8 <= p1; p += 8) {
    int s[8];
#pragma unroll
    for (int j = 0; j < 8; ++j)
      s[j] = __builtin_amdgcn_readfirstlane((int)(csrSD[p + j] & 0xFFFFu));
    ushort2 v[8];
#pragma unroll
    for (int j = 0; j < 8; ++j) {
      const ushort* row = h1 + (size_t)s[j] * 128;
      v[j] = *reinterpret_cast<const ushort2*>(row + t * 2);
    }
    float w[8];
#pragma unroll
    for (int j = 0; j < 8; ++j) {
      float e = ss[s[j]] + sdn;
      e = (e > 0.f) ? e : NEG_SLOPE * e;
      w[j] = __expf(e);
    }
#pragma unroll
    for (int j = 0; j < 8; ++j) {
      den += w[j];
      a0 = fmaf(w[j], bf2f(v[j].x), a0);
      a1 = fmaf(w[j], bf2f(v[j].y), a1);
    }
  }
  for (; p + 4 <= p1; p += 4) {
    int s[4];
#pragma unroll
    for (int j = 0; j < 4; ++j)
      s[j] = __builtin_amdgcn_readfirstlane((int)(csrSD[p + j] & 0xFFFFu));
    ushort2 v[4];
#pragma unroll
    for (int j = 0; j < 4; ++j) {
      const ushort* row = h1 + (size_t)s[j] * 128;
      v[j] = *reinterpret_cast<const ushort2*>(row + t * 2);
    }
    float w[4];
#pragma unroll
    for (int j = 0; j < 4; ++j) {
      float e = ss[s[j]] + sdn;
      e = (e > 0.f) ? e : NEG_SLOPE * e;
      w[j] = __expf(e);
    }
#pragma unroll
    for (int j = 0; j < 4; ++j) {
      den += w[j];
      a0 = fmaf(w[j], bf2f(v[j].x), a0);
      a1 = fmaf(w[j], bf2f(v[j].y), a1);
    }
  }
  for (; p < p1; ++p) {
    const int sj = __builtin_amdgcn_readfirstlane((int)(csrSD[p] & 0xFFFFu));
    float e = ss[sj] + sdn;
    e = (e > 0.f) ? e : NEG_SLOPE * e;
    const float wj = __expf(e);
    const ushort* row = h1 + (size_t)sj * 128;
    const ushort2 vj = *reinterpret_cast<const ushort2*>(row + t * 2);
    den += wj;
    a0 = fmaf(wj, bf2f(vj.x), a0);
    a1 = fmaf(wj, bf2f(vj.y), a1);
  }
  const float inv = 1.f / den;
  const float2 bv = reinterpret_cast<const float2*>(b1)[t];
  const float2 xv = x[(size_t)n * 64 + t];
  out[(size_t)n * 64 + t] =
      make_float2(xv.x + fmaf(a0, inv, bv.x), xv.y + fmaf(a1, inv, bv.y));
}

extern "C" void kernel_launch(void* const* d_in, const int* in_sizes, int n_in,
                              void* d_out, int out_size, void* d_ws, size_t ws_size,
                              hipStream_t stream) {
  const float* x      = (const float*)d_in[0];
  const float* W0     = (const float*)d_in[1];
  const float* a_src0 = (const float*)d_in[2];
  const float* a_dst0 = (const float*)d_in[3];
  const float* b0     = (const float*)d_in[4];
  const float* W1     = (const float*)d_in[5];
  const float* a_src1 = (const float*)d_in[6];
  const float* a_dst1 = (const float*)d_in[7];
  const float* b1     = (const float*)d_in[8];
  const int*   ei     = (const int*)d_in[9];
  const int E = in_sizes[9] / 2;
  const int Etot = E + N_NODES;
  float* out = (float*)d_out;
  (void)n_in; (void)out_size; (void)ws_size;

  char* ws = (char*)d_ws;
  size_t off = 0;
  auto alloc = [&](size_t bytes) -> char* {
    char* p = ws + off;
    off += (bytes + 255) & ~(size_t)255;
    return p;
  };
  unsigned char* h0b = (unsigned char*)alloc((size_t)N_NODES * 256);  // fp8
  ushort* hEb  = (ushort*)alloc((size_t)N_NODES * 256 * 2);
  ushort* h1b  = (ushort*)alloc((size_t)N_NODES * 128 * 2);  // bf16 (R17 revert)
  ushort* W0T  = (ushort*)alloc((size_t)256 * 128 * 2);
  ushort* W1T  = (ushort*)alloc((size_t)128 * 256 * 2);
  int* counts  = (int*)alloc((size_t)N_NODES * 4);      // zero-init below
  float* ss0   = (float*)alloc((size_t)N_NODES * 2 * 4);  // direct-stored
  float* sd0   = (float*)alloc((size_t)N_NODES * 2 * 4);
  float* ss1   = (float*)alloc((size_t)N_NODES * 4);
  float* sd1   = (float*)alloc((size_t)N_NODES * 4);
  int* rowptr  = (int*)alloc((size_t)(N_NODES + 1) * 4);
  int* partial = (int*)alloc((size_t)N_NODES * 4);
  int* bsums   = (int*)alloc((size_t)64 * 4);
  ushort* rank = (ushort*)alloc((size_t)Etot * 2);
  unsigned* csrSD = (unsigned*)alloc((size_t)Etot * 4);

  hipMemsetAsync(counts, 0, (size_t)N_NODES * 4, stream);

  // ---- CSR build phase 1 (+ fused weight transposes) ----
  const int nblk = (N_NODES + 1023) / 1024;  // 49
  hist_kernel<<<(Etot + 255) / 256, 256, 0, stream>>>(ei, E, Etot, counts, rank,
                                                      W0, W0T, W1, W1T);
  scan1_kernel<<<nblk, 1024, 0, stream>>>(counts, partial, bsums, N_NODES);
  scan23_kernel<<<(N_NODES + 255) / 256, 256, 0, stream>>>(partial, bsums, rowptr,
                                                           N_NODES, nblk);

  // ---- FUSED: layer-0 gemm (1564 blocks) + scatter (nS blocks) ----
  const int nS = (Etot + 255) / 256;
  const int grid = 3 * NG0 + ((nS > 2 * NG0) ? (nS - 2 * NG0) : 0);
  gemm0_scatter_kernel<<<grid, 256, 0, stream>>>(
      x, W0T, h0b, N_NODES, a_src0, a_dst0, ss0, sd0,
      ei, E, Etot, nS, rowptr, rank, csrSD);

  agg0_kernel<<<N_NODES / 4, 256, 0, stream>>>(h0b, ss0, sd0, rowptr, csrSD, b0, hEb);

  // ---- layer 1 (h1 bf16 — R17 revert) ----
  dim3 g1(1, (N_NODES + 63) / 64);
  gemm_mfma<1, false><<<g1, 256, 0, stream>>>(hEb, W1T, h1b, N_NODES, 128, 256,
                                              a_src1, a_dst1, ss1, sd1);
  agg1_kernel<<<N_NODES / 4, 256, 0, stream>>>(h1b, ss1, sd1, rowptr, csrSD, b1,
                                               (const float2*)x, (float2*)out);
}

// Round 19
// 244.668 us; speedup vs baseline: 1.1600x; 1.0136x over previous
//
#include <hip/hip_runtime.h>

#define N_NODES 50000
#define NEG_SLOPE 0.2f

typedef short s8v __attribute__((ext_vector_type(8)));
typedef float f4v __attribute__((ext_vector_type(4)));

// ---- bf16 helpers (RNE) ---------------------------------------------------
__device__ __forceinline__ ushort f2bf(float f) {
  union { float f; unsigned u; } v; v.f = f;
  return (ushort)((v.u + 0x7FFFu + ((v.u >> 16) & 1u)) >> 16);
}
__device__ __forceinline__ float bf2f(ushort h) {
  union { unsigned u; float f; } v; v.u = ((unsigned)h) << 16;
  return v.f;
}

// ---- fp8 e4m3 helpers (HW cvt, gfx950 OCP e4m3fn) -------------------------
__device__ __forceinline__ unsigned char f2fp8(float f) {
  return (unsigned char)(__builtin_amdgcn_cvt_pk_fp8_f32(f, f, 0, false) & 0xFF);
}

// ---- MFMA GEMM, 64M x 128N tile + direct-store attention scores -----------
// R8/R10-proven structure — DO NOT restructure (R9's rewrite was flaky).
// R17: fp8-h1 REVERTED (R16 failed: layer-1 value path has no downstream
// contraction — fp8 noise lands on out unattenuated). fp8 stays on h0 only.
template <int HEADS, bool AF32>
__global__ __launch_bounds__(256) void gemm_mfma(
    const void* __restrict__ Av, const ushort* __restrict__ BT,
    ushort* __restrict__ C, int M, int N, int K,
    const float* __restrict__ a_src, const float* __restrict__ a_dst,
    float* __restrict__ ss, float* __restrict__ sd) {
  __shared__ ushort As[64][136];   // +8 pad: 16B-aligned, 2-way banks (free)
  __shared__ ushort Bs[128][136];
  const int tid = threadIdx.x;
  const int w = tid >> 6, lane = tid & 63;
  const int q = lane >> 4, r16 = lane & 15;
  const int n0 = blockIdx.x * 128, m0 = blockIdx.y * 64;
  f4v acc[8] = {};
  for (int kc = 0; kc < K; kc += 128) {
#pragma unroll
    for (int i = 0; i < 4; ++i) {
      int c = tid + 256 * i;
      int row = c >> 4, ko = (c & 15) * 8;
      int gm = m0 + row;
      s8v va = {};
      if (gm < M) {
        if (AF32) {
          const float* A = (const float*)Av;
          float4 f0 = *reinterpret_cast<const float4*>(&A[(size_t)gm * K + kc + ko]);
          float4 f1 = *reinterpret_cast<const float4*>(&A[(size_t)gm * K + kc + ko + 4]);
          va[0] = (short)f2bf(f0.x); va[1] = (short)f2bf(f0.y);
          va[2] = (short)f2bf(f0.z); va[3] = (short)f2bf(f0.w);
          va[4] = (short)f2bf(f1.x); va[5] = (short)f2bf(f1.y);
          va[6] = (short)f2bf(f1.z); va[7] = (short)f2bf(f1.w);
        } else {
          const ushort* A = (const ushort*)Av;
          va = *reinterpret_cast<const s8v*>(&A[(size_t)gm * K + kc + ko]);
        }
      }
      *reinterpret_cast<s8v*>(&As[row][ko]) = va;
    }
#pragma unroll
    for (int i = 0; i < 8; ++i) {
      int c = tid + 256 * i;
      int row = c >> 4, ko = (c & 15) * 8;
      s8v vb = *reinterpret_cast<const s8v*>(&BT[(size_t)(n0 + row) * K + kc + ko]);
      *reinterpret_cast<s8v*>(&Bs[row][ko]) = vb;
    }
    __syncthreads();
#pragma unroll
    for (int ks = 0; ks < 4; ++ks) {
      s8v af = *reinterpret_cast<const s8v*>(&As[w * 16 + r16][ks * 32 + q * 8]);
#pragma unroll
      for (int nt = 0; nt < 8; ++nt) {
        s8v bf = *reinterpret_cast<const s8v*>(&Bs[nt * 16 + r16][ks * 32 + q * 8]);
        acc[nt] = __builtin_amdgcn_mfma_f32_16x16x32_bf16(af, bf, acc[nt], 0, 0, 0);
      }
    }
    __syncthreads();
  }
#pragma unroll
  for (int nt = 0; nt < 8; ++nt)
#pragma unroll
    for (int r = 0; r < 4; ++r) {
      int gm = m0 + w * 16 + q * 4 + r;
      if (gm < M) C[(size_t)gm * N + n0 + nt * 16 + r16] = f2bf(acc[nt][r]);
    }
  const int head = n0 >> 7;
  float ps[4] = {0.f, 0.f, 0.f, 0.f}, pd[4] = {0.f, 0.f, 0.f, 0.f};
#pragma unroll
  for (int nt = 0; nt < 8; ++nt) {
    int n = n0 + nt * 16 + r16;
    float as = a_src[n], ad = a_dst[n];
#pragma unroll
    for (int r = 0; r < 4; ++r) {
      ps[r] = fmaf(acc[nt][r], as, ps[r]);
      pd[r] = fmaf(acc[nt][r], ad, pd[r]);
    }
  }
#pragma unroll
  for (int off = 1; off < 16; off <<= 1) {
#pragma unroll
    for (int r = 0; r < 4; ++r) {
      ps[r] += __shfl_xor(ps[r], off);
      pd[r] += __shfl_xor(pd[r], off);
    }
  }
  if (r16 == 0) {
#pragma unroll
    for (int r = 0; r < 4; ++r) {
      int gm = m0 + w * 16 + q * 4 + r;
      if (gm < M) {
        ss[gm * HEADS + head] = ps[r];
        sd[gm * HEADS + head] = pd[r];
      }
    }
  }
}

// ---- FUSED: layer-0 GEMM + CSR scatter in one dispatch --------------------
// R15 fp8-h0 CONFIRMED R8 (-21 us, absmax 0.078 — W1 contraction attenuates).
// R18: A input is precomputed bf16 (xbf from hist) — halves A-load width
// (32->16 B/lane) and deletes 8x f2bf per staging load. Same RNE values
// into MFMA -> numerics bit-identical.
#define NG0 1564  // 2 * ceil(N_NODES/64)
__global__ __launch_bounds__(256) void gemm0_scatter_kernel(
    const ushort* __restrict__ A, const ushort* __restrict__ BT,
    unsigned char* __restrict__ C, int M,
    const float* __restrict__ a_src, const float* __restrict__ a_dst,
    float* __restrict__ ss, float* __restrict__ sd,
    const int* __restrict__ ei, int E, int Etot, int nS,
    const int* __restrict__ rowptr, const ushort* __restrict__ rank,
    unsigned* __restrict__ csrSD) {
  __shared__ ushort As[64][136];
  __shared__ ushort Bs[128][136];
  const int id = blockIdx.x;
  int gemmIdx = -1, sIdx = -1;
  if (id < 3 * NG0) {
    const int g = id / 3, r = id % 3;
    if (r == 0) gemmIdx = g;
    else        sIdx = 2 * g + (r - 1);
  } else {
    sIdx = 2 * NG0 + (id - 3 * NG0);
  }

  if (gemmIdx >= 0) {
    // ---- gemm body (HEADS=2, A bf16, N=256, K=128), x-major block order ----
    const int nb = gemmIdx & 1, mb = gemmIdx >> 1;
    const int tid = threadIdx.x;
    const int w = tid >> 6, lane = tid & 63;
    const int q = lane >> 4, r16 = lane & 15;
    const int n0 = nb * 128, m0 = mb * 64;
    const int N = 256, K = 128;
    f4v acc[8] = {};
    for (int kc = 0; kc < K; kc += 128) {
#pragma unroll
      for (int i = 0; i < 4; ++i) {
        int c = tid + 256 * i;
        int row = c >> 4, ko = (c & 15) * 8;
        int gm = m0 + row;
        s8v va = {};
        if (gm < M)
          va = *reinterpret_cast<const s8v*>(&A[(size_t)gm * K + kc + ko]);
        *reinterpret_cast<s8v*>(&As[row][ko]) = va;
      }
#pragma unroll
      for (int i = 0; i < 8; ++i) {
        int c = tid + 256 * i;
        int row = c >> 4, ko = (c & 15) * 8;
        s8v vb = *reinterpret_cast<const s8v*>(&BT[(size_t)(n0 + row) * K + kc + ko]);
        *reinterpret_cast<s8v*>(&Bs[row][ko]) = vb;
      }
      __syncthreads();
#pragma unroll
      for (int ks = 0; ks < 4; ++ks) {
        s8v af = *reinterpret_cast<const s8v*>(&As[w * 16 + r16][ks * 32 + q * 8]);
#pragma unroll
        for (int nt = 0; nt < 8; ++nt) {
          s8v bf = *reinterpret_cast<const s8v*>(&Bs[nt * 16 + r16][ks * 32 + q * 8]);
          acc[nt] = __builtin_amdgcn_mfma_f32_16x16x32_bf16(af, bf, acc[nt], 0, 0, 0);
        }
      }
      __syncthreads();
    }
#pragma unroll
    for (int nt = 0; nt < 8; ++nt)
#pragma unroll
      for (int r = 0; r < 4; ++r) {
        int gm = m0 + w * 16 + q * 4 + r;
        if (gm < M) C[(size_t)gm * N + n0 + nt * 16 + r16] = f2fp8(acc[nt][r]);
      }
    const int head = n0 >> 7;
    float ps[4] = {0.f, 0.f, 0.f, 0.f}, pd[4] = {0.f, 0.f, 0.f, 0.f};
#pragma unroll
    for (int nt = 0; nt < 8; ++nt) {
      int n = n0 + nt * 16 + r16;
      float as = a_src[n], ad = a_dst[n];
#pragma unroll
      for (int r = 0; r < 4; ++r) {
        ps[r] = fmaf(acc[nt][r], as, ps[r]);
        pd[r] = fmaf(acc[nt][r], ad, pd[r]);
      }
    }
#pragma unroll
    for (int off = 1; off < 16; off <<= 1) {
#pragma unroll
      for (int r = 0; r < 4; ++r) {
        ps[r] += __shfl_xor(ps[r], off);
        pd[r] += __shfl_xor(pd[r], off);
      }
    }
    if (r16 == 0) {
#pragma unroll
      for (int r = 0; r < 4; ++r) {
        int gm = m0 + w * 16 + q * 4 + r;
        if (gm < M) {
          ss[gm * 2 + head] = ps[r];
          sd[gm * 2 + head] = pd[r];
        }
      }
    }
  } else {
    // ---- scatter body (verbatim from R12's scatter_kernel) ----
    if (sIdx >= nS) return;
    int e = sIdx * 256 + threadIdx.x;
    if (e >= Etot) return;
    int s, d;
    if (e < E) { s = ei[e]; d = ei[E + e]; } else { s = d = e - E; }
    csrSD[rowptr[d] + (int)rank[e]] = (unsigned)s | ((unsigned)d << 16);
  }
}

// ------------- CSR build: hist(+rank, +W transposes, +bf16-x) --------------
// R18: also converts x (50000x128 f32) to bf16 xbf — 8 elems/thread,
// threads 0..799999 (< Etot=850000, always covered).
__global__ void hist_kernel(const int* __restrict__ ei, int E, int Etot,
                            int* __restrict__ counts, ushort* __restrict__ rank,
                            const float* __restrict__ W0, ushort* __restrict__ W0T,
                            const float* __restrict__ W1, ushort* __restrict__ W1T,
                            const float* __restrict__ x, ushort* __restrict__ xbf) {
  int i = blockIdx.x * blockDim.x + threadIdx.x;
  if (i < 65536) {
    if (i < 32768) {
      int r = i >> 8, c = i & 255;           // W0: R=128, C=256
      W0T[c * 128 + r] = f2bf(W0[i]);
    } else {
      int j = i - 32768;
      int r = j >> 7, c = j & 127;           // W1: R=256, C=128
      W1T[c * 256 + r] = f2bf(W1[j]);
    }
  }
  if (i < (N_NODES * 128 / 8)) {             // 800000 threads: x -> bf16
    const size_t base = (size_t)i * 8;
    float4 f0 = *reinterpret_cast<const float4*>(&x[base]);
    float4 f1 = *reinterpret_cast<const float4*>(&x[base + 4]);
    s8v vb;
    vb[0] = (short)f2bf(f0.x); vb[1] = (short)f2bf(f0.y);
    vb[2] = (short)f2bf(f0.z); vb[3] = (short)f2bf(f0.w);
    vb[4] = (short)f2bf(f1.x); vb[5] = (short)f2bf(f1.y);
    vb[6] = (short)f2bf(f1.z); vb[7] = (short)f2bf(f1.w);
    *reinterpret_cast<s8v*>(&xbf[base]) = vb;
  }
  int e = i;
  if (e >= Etot) return;
  int d = (e < E) ? ei[E + e] : (e - E);
  rank[e] = (ushort)atomicAdd(&counts[d], 1);  // degree << 65536
}

// R17: wave-shuffle scan (2 barriers instead of 20; exact integer math).
__global__ __launch_bounds__(1024) void scan1_kernel(const int* __restrict__ counts,
                                                     int* __restrict__ partial,
                                                     int* __restrict__ blocksums, int n) {
  __shared__ int wsum[16];
  const int i = blockIdx.x * 1024 + threadIdx.x;
  const int lane = threadIdx.x & 63, wid = threadIdx.x >> 6;
  int s = (i < n) ? counts[i] : 0;
#pragma unroll
  for (int off = 1; off < 64; off <<= 1) {
    int u = __shfl_up(s, off);
    if (lane >= off) s += u;
  }
  if (lane == 63) wsum[wid] = s;
  __syncthreads();
  if (wid == 0 && lane < 16) {
    int ws = wsum[lane];
#pragma unroll
    for (int off = 1; off < 16; off <<= 1) {
      int u = __shfl_up(ws, off);
      if (lane >= off) ws += u;
    }
    wsum[lane] = ws;
  }
  __syncthreads();
  if (wid > 0) s += wsum[wid - 1];
  if (i < n) partial[i] = s;
  if (threadIdx.x == 1023) blocksums[blockIdx.x] = s;
}

__global__ void scan23_kernel(const int* __restrict__ partial,
                              const int* __restrict__ blocksums,
                              int* __restrict__ rowptr, int n, int nb) {
  __shared__ int sb[64];
  int t = threadIdx.x;
  if (t < 64) {
    int v = (t < nb) ? blocksums[t] : 0;
#pragma unroll
    for (int off = 1; off < 64; off <<= 1) {
      int u = __shfl_up(v, off);
      if ((t & 63) >= off) v += u;
    }
    sb[t] = v;
  }
  __syncthreads();
  int i = blockIdx.x * blockDim.x + t;
  if (i == 0) rowptr[0] = 0;
  if (i < n) {
    int b = i >> 10;
    int add = (b > 0) ? sb[b - 1] : 0;
    rowptr[i + 1] = partial[i] + add;
  }
}

// ---- layer-0 aggregation: fp8 h0 gather (R15, confirmed R8) ---------------
__global__ __launch_bounds__(256) void agg0_kernel(
    const unsigned char* __restrict__ h0,   // [N,256] fp8 e4m3
    const float* __restrict__ ss, const float* __restrict__ sd,  // [N,2]
    const int* __restrict__ rowptr, const unsigned* __restrict__ csrSD,
    const float* __restrict__ b0, ushort* __restrict__ hE) {
  const int n = __builtin_amdgcn_readfirstlane(blockIdx.x * 4 + (threadIdx.x >> 6));
  const int t = threadIdx.x & 63;
  const int hd = t >> 5;
  const float2 sdv = *reinterpret_cast<const float2*>(&sd[n * 2]);
  const float sdn = hd ? sdv.y : sdv.x;
  float a0 = 0.f, a1 = 0.f, a2 = 0.f, a3 = 0.f, den = 0.f;
  int p = __builtin_amdgcn_readfirstlane(rowptr[n]);
  const int p1 = __builtin_amdgcn_readfirstlane(rowptr[n + 1]);
  for (; p + 8 <= p1; p += 8) {  // 8 rows in flight per wave
    int s[8];
#pragma unroll
    for (int j = 0; j < 8; ++j)
      s[j] = __builtin_amdgcn_readfirstlane((int)(csrSD[p + j] & 0xFFFFu));
    unsigned v[8];
#pragma unroll
    for (int j = 0; j < 8; ++j) {
      const unsigned char* row = h0 + (size_t)s[j] * 256;   // SGPR base
      v[j] = *reinterpret_cast<const unsigned*>(row + t * 4);
    }
    float w[8];
#pragma unroll
    for (int j = 0; j < 8; ++j) {
      const float2 sv = *reinterpret_cast<const float2*>(&ss[s[j] * 2]);
      float e = (hd ? sv.y : sv.x) + sdn;
      e = (e > 0.f) ? e : NEG_SLOPE * e;
      w[j] = __expf(e);
    }
#pragma unroll
    for (int j = 0; j < 8; ++j) {
      den += w[j];
      a0 = fmaf(w[j], __builtin_amdgcn_cvt_f32_fp8(v[j], 0), a0);
      a1 = fmaf(w[j], __builtin_amdgcn_cvt_f32_fp8(v[j], 1), a1);
      a2 = fmaf(w[j], __builtin_amdgcn_cvt_f32_fp8(v[j], 2), a2);
      a3 = fmaf(w[j], __builtin_amdgcn_cvt_f32_fp8(v[j], 3), a3);
    }
  }
  for (; p + 4 <= p1; p += 4) {
    int s[4];
#pragma unroll
    for (int j = 0; j < 4; ++j)
      s[j] = __builtin_amdgcn_readfirstlane((int)(csrSD[p + j] & 0xFFFFu));
    unsigned v[4];
#pragma unroll
    for (int j = 0; j < 4; ++j) {
      const unsigned char* row = h0 + (size_t)s[j] * 256;
      v[j] = *reinterpret_cast<const unsigned*>(row + t * 4);
    }
    float w[4];
#pragma unroll
    for (int j = 0; j < 4; ++j) {
      const float2 sv = *reinterpret_cast<const float2*>(&ss[s[j] * 2]);
      float e = (hd ? sv.y : sv.x) + sdn;
      e = (e > 0.f) ? e : NEG_SLOPE * e;
      w[j] = __expf(e);
    }
#pragma unroll
    for (int j = 0; j < 4; ++j) {
      den += w[j];
      a0 = fmaf(w[j], __builtin_amdgcn_cvt_f32_fp8(v[j], 0), a0);
      a1 = fmaf(w[j], __builtin_amdgcn_cvt_f32_fp8(v[j], 1), a1);
      a2 = fmaf(w[j], __builtin_amdgcn_cvt_f32_fp8(v[j], 2), a2);
      a3 = fmaf(w[j], __builtin_amdgcn_cvt_f32_fp8(v[j], 3), a3);
    }
  }
  for (; p < p1; ++p) {
    const int sj = __builtin_amdgcn_readfirstlane((int)(csrSD[p] & 0xFFFFu));
    const float2 sv = *reinterpret_cast<const float2*>(&ss[sj * 2]);
    float e = (hd ? sv.y : sv.x) + sdn;
    e = (e > 0.f) ? e : NEG_SLOPE * e;
    const float wj = __expf(e);
    const unsigned char* row = h0 + (size_t)sj * 256;
    const unsigned vj = *reinterpret_cast<const unsigned*>(row + t * 4);
    den += wj;
    a0 = fmaf(wj, __builtin_amdgcn_cvt_f32_fp8(vj, 0), a0);
    a1 = fmaf(wj, __builtin_amdgcn_cvt_f32_fp8(vj, 1), a1);
    a2 = fmaf(wj, __builtin_amdgcn_cvt_f32_fp8(vj, 2), a2);
    a3 = fmaf(wj, __builtin_amdgcn_cvt_f32_fp8(vj, 3), a3);
  }
  const float inv = 1.f / den;
  const float4 bv = reinterpret_cast<const float4*>(b0)[t];
  float o[4] = {fmaf(a0, inv, bv.x), fmaf(a1, inv, bv.y),
                fmaf(a2, inv, bv.z), fmaf(a3, inv, bv.w)};
#pragma unroll
  for (int i = 0; i < 4; ++i) o[i] = (o[i] > 0.f) ? o[i] : (__expf(o[i]) - 1.f);
  ushort4 ov; ov.x = f2bf(o[0]); ov.y = f2bf(o[1]); ov.z = f2bf(o[2]); ov.w = f2bf(o[3]);
  *reinterpret_cast<ushort4*>(&hE[(size_t)n * 256 + t * 4]) = ov;
}

// ---- layer-1 aggregation: bf16 h1 gather (R17: fp8 reverted) --------------
__global__ __launch_bounds__(256) void agg1_kernel(
    const ushort* __restrict__ h1,   // [N,128] bf16
    const float* __restrict__ ss, const float* __restrict__ sd,  // [N]
    const int* __restrict__ rowptr, const unsigned* __restrict__ csrSD,
    const float* __restrict__ b1, const float2* __restrict__ x,
    float2* __restrict__ out) {
  const int n = __builtin_amdgcn_readfirstlane(blockIdx.x * 4 + (threadIdx.x >> 6));
  const int t = threadIdx.x & 63;
  const float sdn = sd[n];
  float a0 = 0.f, a1 = 0.f, den = 0.f;
  int p = __builtin_amdgcn_readfirstlane(rowptr[n]);
  const int p1 = __builtin_amdgcn_readfirstlane(rowptr[n + 1]);
  for (; p + 8 <= p1; p += 8) {
    int s[8];
#pragma unroll
    for (int j = 0; j < 8; ++j)
      s[j] = __builtin_amdgcn_readfirstlane((int)(csrSD[p + j] & 0xFFFFu));
    ushort2 v[8];
#pragma unroll
    for (int j = 0; j < 8; ++j) {
      const ushort* row = h1 + (size_t)s[j] * 128;
      v[j] = *reinterpret_cast<const ushort2*>(row + t * 2);
    }
    float w[8];
#pragma unroll
    for (int j = 0; j < 8; ++j) {
      float e = ss[s[j]] + sdn;
      e = (e > 0.f) ? e : NEG_SLOPE * e;
      w[j] = __expf(e);
    }
#pragma unroll
    for (int j = 0; j < 8; ++j) {
      den += w[j];
      a0 = fmaf(w[j], bf2f(v[j].x), a0);
      a1 = fmaf(w[j], bf2f(v[j].y), a1);
    }
  }
  for (; p + 4 <= p1; p += 4) {
    int s[4];
#pragma unroll
    for (int j = 0; j < 4; ++j)
      s[j] = __builtin_amdgcn_readfirstlane((int)(csrSD[p + j] & 0xFFFFu));
    ushort2 v[4];
#pragma unroll
    for (int j = 0; j < 4; ++j) {
      const ushort* row = h1 + (size_t)s[j] * 128;
      v[j] = *reinterpret_cast<const ushort2*>(row + t * 2);
    }
    float w[4];
#pragma unroll
    for (int j = 0; j < 4; ++j) {
      float e = ss[s[j]] + sdn;
      e = (e > 0.f) ? e : NEG_SLOPE * e;
      w[j] = __expf(e);
    }
#pragma unroll
    for (int j = 0; j < 4; ++j) {
      den += w[j];
      a0 = fmaf(w[j], bf2f(v[j].x), a0);
      a1 = fmaf(w[j], bf2f(v[j].y), a1);
    }
  }
  for (; p < p1; ++p) {
    const int sj = __builtin_amdgcn_readfirstlane((int)(csrSD[p] & 0xFFFFu));
    float e = ss[sj] + sdn;
    e = (e > 0.f) ? e : NEG_SLOPE * e;
    const float wj = __expf(e);
    const ushort* row = h1 + (size_t)sj * 128;
    const ushort2 vj = *reinterpret_cast<const ushort2*>(row + t * 2);
    den += wj;
    a0 = fmaf(wj, bf2f(vj.x), a0);
    a1 = fmaf(wj, bf2f(vj.y), a1);
  }
  const float inv = 1.f / den;
  const float2 bv = reinterpret_cast<const float2*>(b1)[t];
  const float2 xv = x[(size_t)n * 64 + t];
  out[(size_t)n * 64 + t] =
      make_float2(xv.x + fmaf(a0, inv, bv.x), xv.y + fmaf(a1, inv, bv.y));
}

extern "C" void kernel_launch(void* const* d_in, const int* in_sizes, int n_in,
                              void* d_out, int out_size, void* d_ws, size_t ws_size,
                              hipStream_t stream) {
  const float* x      = (const float*)d_in[0];
  const float* W0     = (const float*)d_in[1];
  const float* a_src0 = (const float*)d_in[2];
  const float* a_dst0 = (const float*)d_in[3];
  const float* b0     = (const float*)d_in[4];
  const float* W1     = (const float*)d_in[5];
  const float* a_src1 = (const float*)d_in[6];
  const float* a_dst1 = (const float*)d_in[7];
  const float* b1     = (const float*)d_in[8];
  const int*   ei     = (const int*)d_in[9];
  const int E = in_sizes[9] / 2;
  const int Etot = E + N_NODES;
  float* out = (float*)d_out;
  (void)n_in; (void)out_size; (void)ws_size;

  char* ws = (char*)d_ws;
  size_t off = 0;
  auto alloc = [&](size_t bytes) -> char* {
    char* p = ws + off;
    off += (bytes + 255) & ~(size_t)255;
    return p;
  };
  unsigned char* h0b = (unsigned char*)alloc((size_t)N_NODES * 256);  // fp8
  ushort* hEb  = (ushort*)alloc((size_t)N_NODES * 256 * 2);
  ushort* h1b  = (ushort*)alloc((size_t)N_NODES * 128 * 2);  // bf16 (R17)
  ushort* xbf  = (ushort*)alloc((size_t)N_NODES * 128 * 2);  // R18: bf16 x
  ushort* W0T  = (ushort*)alloc((size_t)256 * 128 * 2);
  ushort* W1T  = (ushort*)alloc((size_t)128 * 256 * 2);
  int* counts  = (int*)alloc((size_t)N_NODES * 4);      // zero-init below
  float* ss0   = (float*)alloc((size_t)N_NODES * 2 * 4);  // direct-stored
  float* sd0   = (float*)alloc((size_t)N_NODES * 2 * 4);
  float* ss1   = (float*)alloc((size_t)N_NODES * 4);
  float* sd1   = (float*)alloc((size_t)N_NODES * 4);
  int* rowptr  = (int*)alloc((size_t)(N_NODES + 1) * 4);
  int* partial = (int*)alloc((size_t)N_NODES * 4);
  int* bsums   = (int*)alloc((size_t)64 * 4);
  ushort* rank = (ushort*)alloc((size_t)Etot * 2);
  unsigned* csrSD = (unsigned*)alloc((size_t)Etot * 4);

  hipMemsetAsync(counts, 0, (size_t)N_NODES * 4, stream);

  // ---- CSR build phase 1 (+ W transposes + bf16-x precompute) ----
  const int nblk = (N_NODES + 1023) / 1024;  // 49
  hist_kernel<<<(Etot + 255) / 256, 256, 0, stream>>>(ei, E, Etot, counts, rank,
                                                      W0, W0T, W1, W1T, x, xbf);
  scan1_kernel<<<nblk, 1024, 0, stream>>>(counts, partial, bsums, N_NODES);
  scan23_kernel<<<(N_NODES + 255) / 256, 256, 0, stream>>>(partial, bsums, rowptr,
                                                           N_NODES, nblk);

  // ---- FUSED: layer-0 gemm (1564 blocks) + scatter (nS blocks) ----
  const int nS = (Etot + 255) / 256;
  const int grid = 3 * NG0 + ((nS > 2 * NG0) ? (nS - 2 * NG0) : 0);
  gemm0_scatter_kernel<<<grid, 256, 0, stream>>>(
      xbf, W0T, h0b, N_NODES, a_src0, a_dst0, ss0, sd0,
      ei, E, Etot, nS, rowptr, rank, csrSD);

  agg0_kernel<<<N_NODES / 4, 256, 0, stream>>>(h0b, ss0, sd0, rowptr, csrSD, b0, hEb);

  // ---- layer 1 (h1 bf16) ----
  dim3 g1(1, (N_NODES + 63) / 64);
  gemm_mfma<1, false><<<g1, 256, 0, stream>>>(hEb, W1T, h1b, N_NODES, 128, 256,
                                              a_src1, a_dst1, ss1, sd1);
  agg1_kernel<<<N_NODES / 4, 256, 0, stream>>>(h1b, ss1, sd1, rowptr, csrSD, b1,
                                               (const float2*)x, (float2*)out);
}

// Round 20
// 238.720 us; speedup vs baseline: 1.1889x; 1.0249x over previous
//
#include <hip/hip_runtime.h>

#define N_NODES 50000
#define NEG_SLOPE 0.2f

typedef short s8v __attribute__((ext_vector_type(8)));
typedef float f4v __attribute__((ext_vector_type(4)));

// ---- bf16 helpers (RNE) ---------------------------------------------------
__device__ __forceinline__ ushort f2bf(float f) {
  union { float f; unsigned u; } v; v.f = f;
  return (ushort)((v.u + 0x7FFFu + ((v.u >> 16) & 1u)) >> 16);
}
__device__ __forceinline__ float bf2f(ushort h) {
  union { unsigned u; float f; } v; v.u = ((unsigned)h) << 16;
  return v.f;
}

// ---- fp8 e4m3 helpers (HW cvt, gfx950 OCP e4m3fn) -------------------------
__device__ __forceinline__ unsigned char f2fp8(float f) {
  return (unsigned char)(__builtin_amdgcn_cvt_pk_fp8_f32(f, f, 0, false) & 0xFF);
}

// ---- both weight transposes in one kernel (R0-proven, resurrected R19) ----
__global__ void convT2_kernel(const float* __restrict__ W0, ushort* __restrict__ W0T,
                              const float* __restrict__ W1, ushort* __restrict__ W1T) {
  int i = blockIdx.x * blockDim.x + threadIdx.x;
  if (i < 32768) {
    int r = i >> 8, c = i & 255;           // W0: R=128, C=256
    W0T[c * 128 + r] = f2bf(W0[i]);
  } else {
    int j = i - 32768;
    int r = j >> 7, c = j & 127;           // W1: R=256, C=128
    W1T[c * 256 + r] = f2bf(W1[j]);
  }
}

// ---- MFMA GEMM, 64M x 128N tile + direct-store attention scores -----------
// R8/R10-proven structure — DO NOT restructure (R9's rewrite was flaky).
// R17: fp8-h1 REVERTED (layer-1 value path has no downstream contraction).
template <int HEADS, bool AF32>
__global__ __launch_bounds__(256) void gemm_mfma(
    const void* __restrict__ Av, const ushort* __restrict__ BT,
    ushort* __restrict__ C, int M, int N, int K,
    const float* __restrict__ a_src, const float* __restrict__ a_dst,
    float* __restrict__ ss, float* __restrict__ sd) {
  __shared__ ushort As[64][136];   // +8 pad: 16B-aligned, 2-way banks (free)
  __shared__ ushort Bs[128][136];
  const int tid = threadIdx.x;
  const int w = tid >> 6, lane = tid & 63;
  const int q = lane >> 4, r16 = lane & 15;
  const int n0 = blockIdx.x * 128, m0 = blockIdx.y * 64;
  f4v acc[8] = {};
  for (int kc = 0; kc < K; kc += 128) {
#pragma unroll
    for (int i = 0; i < 4; ++i) {
      int c = tid + 256 * i;
      int row = c >> 4, ko = (c & 15) * 8;
      int gm = m0 + row;
      s8v va = {};
      if (gm < M) {
        if (AF32) {
          const float* A = (const float*)Av;
          float4 f0 = *reinterpret_cast<const float4*>(&A[(size_t)gm * K + kc + ko]);
          float4 f1 = *reinterpret_cast<const float4*>(&A[(size_t)gm * K + kc + ko + 4]);
          va[0] = (short)f2bf(f0.x); va[1] = (short)f2bf(f0.y);
          va[2] = (short)f2bf(f0.z); va[3] = (short)f2bf(f0.w);
          va[4] = (short)f2bf(f1.x); va[5] = (short)f2bf(f1.y);
          va[6] = (short)f2bf(f1.z); va[7] = (short)f2bf(f1.w);
        } else {
          const ushort* A = (const ushort*)Av;
          va = *reinterpret_cast<const s8v*>(&A[(size_t)gm * K + kc + ko]);
        }
      }
      *reinterpret_cast<s8v*>(&As[row][ko]) = va;
    }
#pragma unroll
    for (int i = 0; i < 8; ++i) {
      int c = tid + 256 * i;
      int row = c >> 4, ko = (c & 15) * 8;
      s8v vb = *reinterpret_cast<const s8v*>(&BT[(size_t)(n0 + row) * K + kc + ko]);
      *reinterpret_cast<s8v*>(&Bs[row][ko]) = vb;
    }
    __syncthreads();
#pragma unroll
    for (int ks = 0; ks < 4; ++ks) {
      s8v af = *reinterpret_cast<const s8v*>(&As[w * 16 + r16][ks * 32 + q * 8]);
#pragma unroll
      for (int nt = 0; nt < 8; ++nt) {
        s8v bf = *reinterpret_cast<const s8v*>(&Bs[nt * 16 + r16][ks * 32 + q * 8]);
        acc[nt] = __builtin_amdgcn_mfma_f32_16x16x32_bf16(af, bf, acc[nt], 0, 0, 0);
      }
    }
    __syncthreads();
  }
#pragma unroll
  for (int nt = 0; nt < 8; ++nt)
#pragma unroll
    for (int r = 0; r < 4; ++r) {
      int gm = m0 + w * 16 + q * 4 + r;
      if (gm < M) C[(size_t)gm * N + n0 + nt * 16 + r16] = f2bf(acc[nt][r]);
    }
  const int head = n0 >> 7;
  float ps[4] = {0.f, 0.f, 0.f, 0.f}, pd[4] = {0.f, 0.f, 0.f, 0.f};
#pragma unroll
  for (int nt = 0; nt < 8; ++nt) {
    int n = n0 + nt * 16 + r16;
    float as = a_src[n], ad = a_dst[n];
#pragma unroll
    for (int r = 0; r < 4; ++r) {
      ps[r] = fmaf(acc[nt][r], as, ps[r]);
      pd[r] = fmaf(acc[nt][r], ad, pd[r]);
    }
  }
#pragma unroll
  for (int off = 1; off < 16; off <<= 1) {
#pragma unroll
    for (int r = 0; r < 4; ++r) {
      ps[r] += __shfl_xor(ps[r], off);
      pd[r] += __shfl_xor(pd[r], off);
    }
  }
  if (r16 == 0) {
#pragma unroll
    for (int r = 0; r < 4; ++r) {
      int gm = m0 + w * 16 + q * 4 + r;
      if (gm < M) {
        ss[gm * HEADS + head] = ps[r];
        sd[gm * HEADS + head] = pd[r];
      }
    }
  }
}

// ---- MEGA: layer-0 GEMM + hist(atomic rank) in one dispatch ---------------
// R19 theory: hist is pure atomic-return latency (48 us, VALUBusy 1.4%,
// 1.16 TB/s) — zero resource overlap with gemm0's MFMA+staging. Interleave
// 1 gemm : 2 hist for per-CU co-residency (m114: stalled waves + MFMA waves
// co-schedule free). gemm body = R17-verified AF32 path (bit-identical
// numerics); hist body = rank atomics only (transposes -> convT2, scatter
// -> standalone). fp8-h0 out CONFIRMED R8.
#define NG0 1564  // 2 * ceil(N_NODES/64)
__global__ __launch_bounds__(256) void gemm0_hist_kernel(
    const float* __restrict__ A, const ushort* __restrict__ BT,
    unsigned char* __restrict__ C, int M,
    const float* __restrict__ a_src, const float* __restrict__ a_dst,
    float* __restrict__ ss, float* __restrict__ sd,
    const int* __restrict__ ei, int E, int Etot, int nH,
    int* __restrict__ counts, ushort* __restrict__ rank) {
  __shared__ ushort As[64][136];
  __shared__ ushort Bs[128][136];
  const int id = blockIdx.x;
  int gemmIdx = -1, hIdx = -1;
  if (id < 3 * NG0) {
    const int g = id / 3, r = id % 3;
    if (r == 0) gemmIdx = g;
    else        hIdx = 2 * g + (r - 1);
  } else {
    hIdx = 2 * NG0 + (id - 3 * NG0);
  }

  if (gemmIdx >= 0) {
    // ---- gemm body (HEADS=2, AF32, N=256, K=128), x-major block order ----
    const int nb = gemmIdx & 1, mb = gemmIdx >> 1;
    const int tid = threadIdx.x;
    const int w = tid >> 6, lane = tid & 63;
    const int q = lane >> 4, r16 = lane & 15;
    const int n0 = nb * 128, m0 = mb * 64;
    const int N = 256, K = 128;
    f4v acc[8] = {};
    for (int kc = 0; kc < K; kc += 128) {
#pragma unroll
      for (int i = 0; i < 4; ++i) {
        int c = tid + 256 * i;
        int row = c >> 4, ko = (c & 15) * 8;
        int gm = m0 + row;
        s8v va = {};
        if (gm < M) {
          float4 f0 = *reinterpret_cast<const float4*>(&A[(size_t)gm * K + kc + ko]);
          float4 f1 = *reinterpret_cast<const float4*>(&A[(size_t)gm * K + kc + ko + 4]);
          va[0] = (short)f2bf(f0.x); va[1] = (short)f2bf(f0.y);
          va[2] = (short)f2bf(f0.z); va[3] = (short)f2bf(f0.w);
          va[4] = (short)f2bf(f1.x); va[5] = (short)f2bf(f1.y);
          va[6] = (short)f2bf(f1.z); va[7] = (short)f2bf(f1.w);
        }
        *reinterpret_cast<s8v*>(&As[row][ko]) = va;
      }
#pragma unroll
      for (int i = 0; i < 8; ++i) {
        int c = tid + 256 * i;
        int row = c >> 4, ko = (c & 15) * 8;
        s8v vb = *reinterpret_cast<const s8v*>(&BT[(size_t)(n0 + row) * K + kc + ko]);
        *reinterpret_cast<s8v*>(&Bs[row][ko]) = vb;
      }
      __syncthreads();
#pragma unroll
      for (int ks = 0; ks < 4; ++ks) {
        s8v af = *reinterpret_cast<const s8v*>(&As[w * 16 + r16][ks * 32 + q * 8]);
#pragma unroll
        for (int nt = 0; nt < 8; ++nt) {
          s8v bf = *reinterpret_cast<const s8v*>(&Bs[nt * 16 + r16][ks * 32 + q * 8]);
          acc[nt] = __builtin_amdgcn_mfma_f32_16x16x32_bf16(af, bf, acc[nt], 0, 0, 0);
        }
      }
      __syncthreads();
    }
#pragma unroll
    for (int nt = 0; nt < 8; ++nt)
#pragma unroll
      for (int r = 0; r < 4; ++r) {
        int gm = m0 + w * 16 + q * 4 + r;
        if (gm < M) C[(size_t)gm * N + n0 + nt * 16 + r16] = f2fp8(acc[nt][r]);
      }
    const int head = n0 >> 7;
    float ps[4] = {0.f, 0.f, 0.f, 0.f}, pd[4] = {0.f, 0.f, 0.f, 0.f};
#pragma unroll
    for (int nt = 0; nt < 8; ++nt) {
      int n = n0 + nt * 16 + r16;
      float as = a_src[n], ad = a_dst[n];
#pragma unroll
      for (int r = 0; r < 4; ++r) {
        ps[r] = fmaf(acc[nt][r], as, ps[r]);
        pd[r] = fmaf(acc[nt][r], ad, pd[r]);
      }
    }
#pragma unroll
    for (int off = 1; off < 16; off <<= 1) {
#pragma unroll
      for (int r = 0; r < 4; ++r) {
        ps[r] += __shfl_xor(ps[r], off);
        pd[r] += __shfl_xor(pd[r], off);
      }
    }
    if (r16 == 0) {
#pragma unroll
      for (int r = 0; r < 4; ++r) {
        int gm = m0 + w * 16 + q * 4 + r;
        if (gm < M) {
          ss[gm * 2 + head] = ps[r];
          sd[gm * 2 + head] = pd[r];
        }
      }
    }
  } else {
    // ---- hist body: rank atomics only (latency-bound; hides under gemm) --
    if (hIdx >= nH) return;
    int e = hIdx * 256 + threadIdx.x;
    if (e >= Etot) return;
    int d = (e < E) ? ei[E + e] : (e - E);
    rank[e] = (ushort)atomicAdd(&counts[d], 1);
  }
}

// ---- standalone scatter (R12-proven body) ---------------------------------
__global__ void scatter_kernel(const int* __restrict__ ei, int E, int Etot,
                               const int* __restrict__ rowptr,
                               const ushort* __restrict__ rank,
                               unsigned* __restrict__ csrSD) {
  int e = blockIdx.x * blockDim.x + threadIdx.x;
  if (e >= Etot) return;
  int s, d;
  if (e < E) { s = ei[e]; d = ei[E + e]; } else { s = d = e - E; }
  csrSD[rowptr[d] + (int)rank[e]] = (unsigned)s | ((unsigned)d << 16);
}

// R17: wave-shuffle scan (2 barriers instead of 20; exact integer math).
__global__ __launch_bounds__(1024) void scan1_kernel(const int* __restrict__ counts,
                                                     int* __restrict__ partial,
                                                     int* __restrict__ blocksums, int n) {
  __shared__ int wsum[16];
  const int i = blockIdx.x * 1024 + threadIdx.x;
  const int lane = threadIdx.x & 63, wid = threadIdx.x >> 6;
  int s = (i < n) ? counts[i] : 0;
#pragma unroll
  for (int off = 1; off < 64; off <<= 1) {
    int u = __shfl_up(s, off);
    if (lane >= off) s += u;
  }
  if (lane == 63) wsum[wid] = s;
  __syncthreads();
  if (wid == 0 && lane < 16) {
    int ws = wsum[lane];
#pragma unroll
    for (int off = 1; off < 16; off <<= 1) {
      int u = __shfl_up(ws, off);
      if (lane >= off) ws += u;
    }
    wsum[lane] = ws;
  }
  __syncthreads();
  if (wid > 0) s += wsum[wid - 1];
  if (i < n) partial[i] = s;
  if (threadIdx.x == 1023) blocksums[blockIdx.x] = s;
}

__global__ void scan23_kernel(const int* __restrict__ partial,
                              const int* __restrict__ blocksums,
                              int* __restrict__ rowptr, int n, int nb) {
  __shared__ int sb[64];
  int t = threadIdx.x;
  if (t < 64) {
    int v = (t < nb) ? blocksums[t] : 0;
#pragma unroll
    for (int off = 1; off < 64; off <<= 1) {
      int u = __shfl_up(v, off);
      if ((t & 63) >= off) v += u;
    }
    sb[t] = v;
  }
  __syncthreads();
  int i = blockIdx.x * blockDim.x + t;
  if (i == 0) rowptr[0] = 0;
  if (i < n) {
    int b = i >> 10;
    int add = (b > 0) ? sb[b - 1] : 0;
    rowptr[i + 1] = partial[i] + add;
  }
}

// ---- layer-0 aggregation: fp8 h0 gather (R15, confirmed R8) ---------------
__global__ __launch_bounds__(256) void agg0_kernel(
    const unsigned char* __restrict__ h0,   // [N,256] fp8 e4m3
    const float* __restrict__ ss, const float* __restrict__ sd,  // [N,2]
    const int* __restrict__ rowptr, const unsigned* __restrict__ csrSD,
    const float* __restrict__ b0, ushort* __restrict__ hE) {
  const int n = __builtin_amdgcn_readfirstlane(blockIdx.x * 4 + (threadIdx.x >> 6));
  const int t = threadIdx.x & 63;
  const int hd = t >> 5;
  const float2 sdv = *reinterpret_cast<const float2*>(&sd[n * 2]);
  const float sdn = hd ? sdv.y : sdv.x;
  float a0 = 0.f, a1 = 0.f, a2 = 0.f, a3 = 0.f, den = 0.f;
  int p = __builtin_amdgcn_readfirstlane(rowptr[n]);
  const int p1 = __builtin_amdgcn_readfirstlane(rowptr[n + 1]);
  for (; p + 8 <= p1; p += 8) {  // 8 rows in flight per wave
    int s[8];
#pragma unroll
    for (int j = 0; j < 8; ++j)
      s[j] = __builtin_amdgcn_readfirstlane((int)(csrSD[p + j] & 0xFFFFu));
    unsigned v[8];
#pragma unroll
    for (int j = 0; j < 8; ++j) {
      const unsigned char* row = h0 + (size_t)s[j] * 256;   // SGPR base
      v[j] = *reinterpret_cast<const unsigned*>(row + t * 4);
    }
    float w[8];
#pragma unroll
    for (int j = 0; j < 8; ++j) {
      const float2 sv = *reinterpret_cast<const float2*>(&ss[s[j] * 2]);
      float e = (hd ? sv.y : sv.x) + sdn;
      e = (e > 0.f) ? e : NEG_SLOPE * e;
      w[j] = __expf(e);
    }
#pragma unroll
    for (int j = 0; j < 8; ++j) {
      den += w[j];
      a0 = fmaf(w[j], __builtin_amdgcn_cvt_f32_fp8(v[j], 0), a0);
      a1 = fmaf(w[j], __builtin_amdgcn_cvt_f32_fp8(v[j], 1), a1);
      a2 = fmaf(w[j], __builtin_amdgcn_cvt_f32_fp8(v[j], 2), a2);
      a3 = fmaf(w[j], __builtin_amdgcn_cvt_f32_fp8(v[j], 3), a3);
    }
  }
  for (; p + 4 <= p1; p += 4) {
    int s[4];
#pragma unroll
    for (int j = 0; j < 4; ++j)
      s[j] = __builtin_amdgcn_readfirstlane((int)(csrSD[p + j] & 0xFFFFu));
    unsigned v[4];
#pragma unroll
    for (int j = 0; j < 4; ++j) {
      const unsigned char* row = h0 + (size_t)s[j] * 256;
      v[j] = *reinterpret_cast<const unsigned*>(row + t * 4);
    }
    float w[4];
#pragma unroll
    for (int j = 0; j < 4; ++j) {
      const float2 sv = *reinterpret_cast<const float2*>(&ss[s[j] * 2]);
      float e = (hd ? sv.y : sv.x) + sdn;
      e = (e > 0.f) ? e : NEG_SLOPE * e;
      w[j] = __expf(e);
    }
#pragma unroll
    for (int j = 0; j < 4; ++j) {
      den += w[j];
      a0 = fmaf(w[j], __builtin_amdgcn_cvt_f32_fp8(v[j], 0), a0);
      a1 = fmaf(w[j], __builtin_amdgcn_cvt_f32_fp8(v[j], 1), a1);
      a2 = fmaf(w[j], __builtin_amdgcn_cvt_f32_fp8(v[j], 2), a2);
      a3 = fmaf(w[j], __builtin_amdgcn_cvt_f32_fp8(v[j], 3), a3);
    }
  }
  for (; p < p1; ++p) {
    const int sj = __builtin_amdgcn_readfirstlane((int)(csrSD[p] & 0xFFFFu));
    const float2 sv = *reinterpret_cast<const float2*>(&ss[sj * 2]);
    float e = (hd ? sv.y : sv.x) + sdn;
    e = (e > 0.f) ? e : NEG_SLOPE * e;
    const float wj = __expf(e);
    const unsigned char* row = h0 + (size_t)sj * 256;
    const unsigned vj = *reinterpret_cast<const unsigned*>(row + t * 4);
    den += wj;
    a0 = fmaf(wj, __builtin_amdgcn_cvt_f32_fp8(vj, 0), a0);
    a1 = fmaf(wj, __builtin_amdgcn_cvt_f32_fp8(vj, 1), a1);
    a2 = fmaf(wj, __builtin_amdgcn_cvt_f32_fp8(vj, 2), a2);
    a3 = fmaf(wj, __builtin_amdgcn_cvt_f32_fp8(vj, 3), a3);
  }
  const float inv = 1.f / den;
  const float4 bv = reinterpret_cast<const float4*>(b0)[t];
  float o[4] = {fmaf(a0, inv, bv.x), fmaf(a1, inv, bv.y),
                fmaf(a2, inv, bv.z), fmaf(a3, inv, bv.w)};
#pragma unroll
  for (int i = 0; i < 4; ++i) o[i] = (o[i] > 0.f) ? o[i] : (__expf(o[i]) - 1.f);
  ushort4 ov; ov.x = f2bf(o[0]); ov.y = f2bf(o[1]); ov.z = f2bf(o[2]); ov.w = f2bf(o[3]);
  *reinterpret_cast<ushort4*>(&hE[(size_t)n * 256 + t * 4]) = ov;
}

// ---- layer-1 aggregation: bf16 h1 gather (R17: fp8 reverted) --------------
__global__ __launch_bounds__(256) void agg1_kernel(
    const ushort* __restrict__ h1,   // [N,128] bf16
    const float* __restrict__ ss, const float* __restrict__ sd,  // [N]
    const int* __restrict__ rowptr, const unsigned* __restrict__ csrSD,
    const float* __restrict__ b1, const float2* __restrict__ x,
    float2* __restrict__ out) {
  const int n = __builtin_amdgcn_readfirstlane(blockIdx.x * 4 + (threadIdx.x >> 6));
  const int t = threadIdx.x & 63;
  const float sdn = sd[n];
  float a0 = 0.f, a1 = 0.f, den = 0.f;
  int p = __builtin_amdgcn_readfirstlane(rowptr[n]);
  const int p1 = __builtin_amdgcn_readfirstlane(rowptr[n + 1]);
  for (; p + 8 <= p1; p += 8) {
    int s[8];
#pragma unroll
    for (int j = 0; j < 8; ++j)
      s[j] = __builtin_amdgcn_readfirstlane((int)(csrSD[p + j] & 0xFFFFu));
    ushort2 v[8];
#pragma unroll
    for (int j = 0; j < 8; ++j) {
      const ushort* row = h1 + (size_t)s[j] * 128;
      v[j] = *reinterpret_cast<const ushort2*>(row + t * 2);
    }
    float w[8];
#pragma unroll
    for (int j = 0; j < 8; ++j) {
      float e = ss[s[j]] + sdn;
      e = (e > 0.f) ? e : NEG_SLOPE * e;
      w[j] = __expf(e);
    }
#pragma unroll
    for (int j = 0; j < 8; ++j) {
      den += w[j];
      a0 = fmaf(w[j], bf2f(v[j].x), a0);
      a1 = fmaf(w[j], bf2f(v[j].y), a1);
    }
  }
  for (; p + 4 <= p1; p += 4) {
    int s[4];
#pragma unroll
    for (int j = 0; j < 4; ++j)
      s[j] = __builtin_amdgcn_readfirstlane((int)(csrSD[p + j] & 0xFFFFu));
    ushort2 v[4];
#pragma unroll
    for (int j = 0; j < 4; ++j) {
      const ushort* row = h1 + (size_t)s[j] * 128;
      v[j] = *reinterpret_cast<const ushort2*>(row + t * 2);
    }
    float w[4];
#pragma unroll
    for (int j = 0; j < 4; ++j) {
      float e = ss[s[j]] + sdn;
      e = (e > 0.f) ? e : NEG_SLOPE * e;
      w[j] = __expf(e);
    }
#pragma unroll
    for (int j = 0; j < 4; ++j) {
      den += w[j];
      a0 = fmaf(w[j], bf2f(v[j].x), a0);
      a1 = fmaf(w[j], bf2f(v[j].y), a1);
    }
  }
  for (; p < p1; ++p) {
    const int sj = __builtin_amdgcn_readfirstlane((int)(csrSD[p] & 0xFFFFu));
    float e = ss[sj] + sdn;
    e = (e > 0.f) ? e : NEG_SLOPE * e;
    const float wj = __expf(e);
    const ushort* row = h1 + (size_t)sj * 128;
    const ushort2 vj = *reinterpret_cast<const ushort2*>(row + t * 2);
    den += wj;
    a0 = fmaf(wj, bf2f(vj.x), a0);
    a1 = fmaf(wj, bf2f(vj.y), a1);
  }
  const float inv = 1.f / den;
  const float2 bv = reinterpret_cast<const float2*>(b1)[t];
  const float2 xv = x[(size_t)n * 64 + t];
  out[(size_t)n * 64 + t] =
      make_float2(xv.x + fmaf(a0, inv, bv.x), xv.y + fmaf(a1, inv, bv.y));
}

extern "C" void kernel_launch(void* const* d_in, const int* in_sizes, int n_in,
                              void* d_out, int out_size, void* d_ws, size_t ws_size,
                              hipStream_t stream) {
  const float* x      = (const float*)d_in[0];
  const float* W0     = (const float*)d_in[1];
  const float* a_src0 = (const float*)d_in[2];
  const float* a_dst0 = (const float*)d_in[3];
  const float* b0     = (const float*)d_in[4];
  const float* W1     = (const float*)d_in[5];
  const float* a_src1 = (const float*)d_in[6];
  const float* a_dst1 = (const float*)d_in[7];
  const float* b1     = (const float*)d_in[8];
  const int*   ei     = (const int*)d_in[9];
  const int E = in_sizes[9] / 2;
  const int Etot = E + N_NODES;
  float* out = (float*)d_out;
  (void)n_in; (void)out_size; (void)ws_size;

  char* ws = (char*)d_ws;
  size_t off = 0;
  auto alloc = [&](size_t bytes) -> char* {
    char* p = ws + off;
    off += (bytes + 255) & ~(size_t)255;
    return p;
  };
  unsigned char* h0b = (unsigned char*)alloc((size_t)N_NODES * 256);  // fp8
  ushort* hEb  = (ushort*)alloc((size_t)N_NODES * 256 * 2);
  ushort* h1b  = (ushort*)alloc((size_t)N_NODES * 128 * 2);  // bf16 (R17)
  ushort* W0T  = (ushort*)alloc((size_t)256 * 128 * 2);
  ushort* W1T  = (ushort*)alloc((size_t)128 * 256 * 2);
  int* counts  = (int*)alloc((size_t)N_NODES * 4);      // zero-init below
  float* ss0   = (float*)alloc((size_t)N_NODES * 2 * 4);  // direct-stored
  float* sd0   = (float*)alloc((size_t)N_NODES * 2 * 4);
  float* ss1   = (float*)alloc((size_t)N_NODES * 4);
  float* sd1   = (float*)alloc((size_t)N_NODES * 4);
  int* rowptr  = (int*)alloc((size_t)(N_NODES + 1) * 4);
  int* partial = (int*)alloc((size_t)N_NODES * 4);
  int* bsums   = (int*)alloc((size_t)64 * 4);
  ushort* rank = (ushort*)alloc((size_t)Etot * 2);
  unsigned* csrSD = (unsigned*)alloc((size_t)Etot * 4);

  hipMemsetAsync(counts, 0, (size_t)N_NODES * 4, stream);

  // ---- prep: weight transposes (must precede mega's gemm blocks) ----
  convT2_kernel<<<65536 / 256, 256, 0, stream>>>(W0, W0T, W1, W1T);

  // ---- MEGA: layer-0 gemm (1564 blocks) + hist atomics (nH blocks) ----
  const int nH = (Etot + 255) / 256;   // 3321
  const int grid = 3 * NG0 + ((nH > 2 * NG0) ? (nH - 2 * NG0) : 0);
  gemm0_hist_kernel<<<grid, 256, 0, stream>>>(
      x, W0T, h0b, N_NODES, a_src0, a_dst0, ss0, sd0,
      ei, E, Etot, nH, counts, rank);

  // ---- CSR scan + scatter ----
  const int nblk = (N_NODES + 1023) / 1024;  // 49
  scan1_kernel<<<nblk, 1024, 0, stream>>>(counts, partial, bsums, N_NODES);
  scan23_kernel<<<(N_NODES + 255) / 256, 256, 0, stream>>>(partial, bsums, rowptr,
                                                           N_NODES, nblk);
  scatter_kernel<<<nH, 256, 0, stream>>>(ei, E, Etot, rowptr, rank, csrSD);

  agg0_kernel<<<N_NODES / 4, 256, 0, stream>>>(h0b, ss0, sd0, rowptr, csrSD, b0, hEb);

  // ---- layer 1 (h1 bf16) ----
  dim3 g1(1, (N_NODES + 63) / 64);
  gemm_mfma<1, false><<<g1, 256, 0, stream>>>(hEb, W1T, h1b, N_NODES, 128, 256,
                                              a_src1, a_dst1, ss1, sd1);
  agg1_kernel<<<N_NODES / 4, 256, 0, stream>>>(h1b, ss1, sd1, rowptr, csrSD, b1,
                                               (const float2*)x, (float2*)out);
}